// Round 14
// baseline (857.675 us; speedup 1.0000x reference)
//
#include <hip/hip_runtime.h>

typedef __bf16 bf16_t;
typedef __attribute__((ext_vector_type(8))) __bf16 bf16x8;
typedef __attribute__((ext_vector_type(4))) __bf16 bf16x4;
typedef __attribute__((ext_vector_type(4))) float f32x4;

#define EPS 1e-3f
#define OUT1 (4096L*2048)
#define OUT2 (OUT1 + 4096L*2176)

__device__ __forceinline__ float sigmoidf_(float x){ return 1.0f/(1.0f+expf(-x)); }

__device__ __forceinline__ void glds16(const void* g, void* l) {
  __builtin_amdgcn_global_load_lds(
      (__attribute__((address_space(1))) void*)g,
      (__attribute__((address_space(3))) void*)l, 16, 0, 0);
}

// ---------------- build A = [x | h | hyper_h] as bf16, [4096][3200] ----------------
__global__ __launch_bounds__(256) void build_A_k(const float* __restrict__ x,
                                                 const float* __restrict__ th,
                                                 bf16_t* __restrict__ A) {
  const int total = 4096 * 800;  // groups of 4 elements
  for (int i = blockIdx.x * blockDim.x + threadIdx.x; i < total; i += gridDim.x * blockDim.x) {
    int b = i / 800;
    int c4 = (i - b * 800) * 4;
    float4 v;
    if (c4 < 1024)       v = *(const float4*)(x  + (long)b*1024 + c4);
    else if (c4 < 3072)  v = *(const float4*)(th + (long)b*2176 + (c4 - 1024));
    else                 v = *(const float4*)(th + (long)b*2176 + 2048 + (c4 - 3072));
    bf16x4 o = { (bf16_t)v.x, (bf16_t)v.y, (bf16_t)v.z, (bf16_t)v.w };
    *(bf16x4*)(A + (long)i*4) = o;
  }
}

// ---------------- transpose + convert: in fp32 [K][N] (split at K1) -> out bf16 [N][Ktot] ----------------
__global__ __launch_bounds__(256) void transpose_conv_k(const float* __restrict__ in1, int K1,
                                                        const float* __restrict__ in2, int Ktot,
                                                        int N, bf16_t* __restrict__ out) {
  __shared__ float tile[32][33];
  int n0 = blockIdx.x * 32, k0 = blockIdx.y * 32;
  int tx = threadIdx.x, ty = threadIdx.y;  // (32,8)
  #pragma unroll
  for (int r = 0; r < 4; ++r) {
    int k = k0 + ty + r*8;
    float v = (k < K1) ? in1[(long)k*N + n0 + tx] : in2[(long)(k - K1)*N + n0 + tx];
    tile[ty + r*8][tx] = v;
  }
  __syncthreads();
  #pragma unroll
  for (int r = 0; r < 4; ++r) {
    int n = n0 + ty + r*8;
    out[(long)n*Ktot + k0 + tx] = (bf16_t)tile[tx][ty + r*8];
  }
}

// ---------------- bf16 GEMM, split-K via blockIdx.z, 2-phase LDS double-buffer ----------------
template<typename T>
__global__ __launch_bounds__(256) void gemm_bf16_k(const bf16_t* __restrict__ A, int lda,
                                                   const bf16_t* __restrict__ Bt, int ldb,
                                                   T* __restrict__ C, int ldc, int K,
                                                   long coutStride) {
  const int z = blockIdx.z;
  A  += (long)z * K;
  Bt += (long)z * K;
  C  += (long)z * coutStride;
  __shared__ bf16_t sA[2*128*64];
  __shared__ bf16_t sB[2*128*64];
  const int tid = threadIdx.x;
  const int wave = tid >> 6, lane = tid & 63;
  const int tm = blockIdx.y * 128, tn = blockIdx.x * 128;
  const int wm = wave >> 1, wn = wave & 1;
  const int lq = lane >> 4, lr = lane & 15;

  const bf16_t* Ab = A + (long)tm * lda;
  const bf16_t* Bb = Bt + (long)tn * ldb;

  f32x4 acc[4][4];
  #pragma unroll
  for (int m = 0; m < 4; ++m)
    #pragma unroll
    for (int n = 0; n < 4; ++n) { f32x4 zv = {0.f,0.f,0.f,0.f}; acc[m][n] = zv; }

  int rowS[4], kofS[4], ldsoff[4];
  #pragma unroll
  for (int c = 0; c < 4; ++c) {
    int ci = c*256 + tid;
    int row = ci >> 3, kcp = ci & 7;
    int kcl = kcp ^ (row & 7);           // pre-swizzled source chunk
    rowS[c] = row; kofS[c] = kcl * 8;
    ldsoff[c] = (c*256 + wave*64) * 8;   // wave-uniform element offset
  }

#define H_STAGE(BUF, K0)                                                          \
  { const int k0 = (K0);                                                          \
    _Pragma("unroll")                                                             \
    for (int c = 0; c < 4; ++c) {                                                 \
      glds16(Ab + (long)rowS[c]*lda + k0 + kofS[c], sA + (BUF)*8192 + ldsoff[c]); \
      glds16(Bb + (long)rowS[c]*ldb + k0 + kofS[c], sB + (BUF)*8192 + ldsoff[c]); \
    } }

  const int nk = K >> 6;
  int cur = 0;
  H_STAGE(0, 0)
  __syncthreads();
  for (int kt = 0; kt < nk; ++kt) {
    if (kt + 1 < nk) H_STAGE(cur ^ 1, (kt + 1) << 6)
    const bf16_t* aB = sA + cur*8192;
    const bf16_t* bB = sB + cur*8192;
    #pragma unroll
    for (int kk = 0; kk < 64; kk += 32) {
      const int kc = (kk >> 3) + lq;
      bf16x8 af[4], bf[4];
      #pragma unroll
      for (int m = 0; m < 4; ++m) {
        int row = wm*64 + m*16 + lr;
        af[m] = *(const bf16x8*)(aB + row*64 + ((kc ^ (row & 7)) << 3));
      }
      #pragma unroll
      for (int n = 0; n < 4; ++n) {
        int row = wn*64 + n*16 + lr;
        bf[n] = *(const bf16x8*)(bB + row*64 + ((kc ^ (row & 7)) << 3));
      }
      #pragma unroll
      for (int m = 0; m < 4; ++m)
        #pragma unroll
        for (int n = 0; n < 4; ++n)
          acc[m][n] = __builtin_amdgcn_mfma_f32_16x16x32_bf16(af[m], bf[n], acc[m][n], 0, 0, 0);
    }
    __syncthreads();
    cur ^= 1;
  }
#undef H_STAGE

  // epilogue: C/D layout col=lane&15, row=(lane>>4)*4+i
  #pragma unroll
  for (int m = 0; m < 4; ++m)
    #pragma unroll
    for (int i = 0; i < 4; ++i) {
      long row = tm + wm*64 + m*16 + lq*4 + i;
      #pragma unroll
      for (int n = 0; n < 4; ++n) {
        int col = tn + wn*64 + n*16 + lr;
        C[row*ldc + col] = (T)acc[m][n][i];
      }
    }
}

// ---------------- fused dual-acc GEMM + modulation epilogue, 8-wave 128x128 tile ----------------
// 3-buffer single-barrier stage-early pipeline:
//   iter t: vmcnt(4) [tile t landed; t+1 flying] -> s_barrier ->
//           STAGE(buf[(t+2)%3], t+2) -> COMPUTE(buf[t%3]).
// Race proof: stage targets buf[(t-1)%3]; all waves' iter-(t-1) ds_reads complete
// before their MFMAs (lgkm) which precede the top-of-t barrier => no reader remains.
// Stage issues BEFORE compute -> glds issue overlaps ds_read/MFMA (m196's fine interleave).
__global__ __launch_bounds__(512, 4) void gemm_fused2_k(const bf16_t* __restrict__ A,
                                                        const bf16_t* __restrict__ Wt,   // [8192][3072]
                                                        const bf16_t* __restrict__ Zbig,
                                                        const bf16_t* __restrict__ Wbig,
                                                        float* __restrict__ gates) {
  __shared__ bf16_t sA[3*128*64];   // 48 KB
  __shared__ bf16_t sB[3*128*64];   // 48 KB
  const int tid = threadIdx.x;
  const int wave = tid >> 6, lane = tid & 63;
  const int tm = blockIdx.y * 128, tn = blockIdx.x * 128;
  const int wm = wave >> 2, wn = wave & 3;
  const int lq = lane >> 4, lr = lane & 15;

  const bf16_t* Ab = A  + (long)tm * 3200;
  const bf16_t* Bb = Wt + (long)tn * 3072;

  f32x4 accX[4][2], accH[4][2];
  #pragma unroll
  for (int m = 0; m < 4; ++m)
    #pragma unroll
    for (int n = 0; n < 2; ++n) { f32x4 zv = {0.f,0.f,0.f,0.f}; accX[m][n] = zv; accH[m][n] = zv; }

  int rowS[2], kofS[2], ldsoff[2];
  #pragma unroll
  for (int c = 0; c < 2; ++c) {
    int ci = c*512 + tid;
    int row = ci >> 3, kcp = ci & 7;
    int kcl = kcp ^ (row & 7);           // pre-swizzled source chunk
    rowS[c] = row; kofS[c] = kcl * 8;
    ldsoff[c] = (c*512 + wave*64) * 8;   // wave-uniform element offset
  }

#define F_STAGE(BUF, K0)                                                            \
  { const int k0 = (K0); const int bo = (BUF)*8192;                                 \
    _Pragma("unroll")                                                               \
    for (int c = 0; c < 2; ++c) {                                                   \
      glds16(Ab + (long)rowS[c]*3200 + k0 + kofS[c], sA + bo + ldsoff[c]);          \
      glds16(Bb + (long)rowS[c]*3072 + k0 + kofS[c], sB + bo + ldsoff[c]);          \
    } }

#define F_COMPUTE(BUF, ACC)                                                         \
  { const bf16_t* aB = sA + (BUF)*8192;                                             \
    const bf16_t* bB = sB + (BUF)*8192;                                             \
    _Pragma("unroll")                                                               \
    for (int kk = 0; kk < 64; kk += 32) {                                           \
      const int kc = (kk >> 3) + lq;                                                \
      bf16x8 af[4], bfr[2];                                                         \
      _Pragma("unroll")                                                             \
      for (int m = 0; m < 4; ++m) {                                                 \
        int row = wm*64 + m*16 + lr;                                                \
        af[m] = *(const bf16x8*)(aB + row*64 + ((kc ^ (row & 7)) << 3));            \
      }                                                                             \
      _Pragma("unroll")                                                             \
      for (int n = 0; n < 2; ++n) {                                                 \
        int row = wn*32 + n*16 + lr;                                                \
        bfr[n] = *(const bf16x8*)(bB + row*64 + ((kc ^ (row & 7)) << 3));           \
      }                                                                             \
      _Pragma("unroll")                                                             \
      for (int m = 0; m < 4; ++m)                                                   \
        _Pragma("unroll")                                                           \
        for (int n = 0; n < 2; ++n)                                                 \
          ACC[m][n] = __builtin_amdgcn_mfma_f32_16x16x32_bf16(af[m], bfr[n], ACC[m][n], 0, 0, 0); \
    } }

#define WAITV4 asm volatile("s_waitcnt vmcnt(4)" ::: "memory")
#define WAITV0 asm volatile("s_waitcnt vmcnt(0)" ::: "memory")
#define BAR()  __builtin_amdgcn_s_barrier()

  int cur = 0;
  F_STAGE(0, 0)
  F_STAGE(1, 64)
  // X phase: kt = 0..15 (kt+2 <= 17 < 48: always stage; kt < 47: always WAITV4)
  for (int kt = 0; kt < 16; ++kt) {
    WAITV4;
    BAR();
    int stg = cur + 2; if (stg >= 3) stg -= 3;
    F_STAGE(stg, (kt + 2) << 6)
    F_COMPUTE(cur, accX)
    cur = (cur == 2) ? 0 : cur + 1;
  }
  // H phase: kt = 16..47
  for (int kt = 16; kt < 48; ++kt) {
    if (kt < 47) { WAITV4; } else { WAITV0; }
    BAR();
    if (kt + 2 < 48) {
      int stg = cur + 2; if (stg >= 3) stg -= 3;
      F_STAGE(stg, (kt + 2) << 6)
    }
    F_COMPUTE(cur, accH)
    cur = (cur == 2) ? 0 : cur + 1;
  }
#undef F_STAGE
#undef F_COMPUTE
#undef WAITV4
#undef WAITV0
#undef BAR

  // ---- modulation epilogue (Z frags reloaded per-n to cap register liveness) ----
  const int g   = tn >> 11;       // gate index (tile lies within one gate; 256|2048)
  const int cg0 = tn & 2047;      // col offset within gate
  #pragma unroll
  for (int m = 0; m < 4; ++m) {
    const bf16_t* Zr = Zbig + ((long)g*4096 + tm + wm*64 + m*16 + lr) * 256;
    #pragma unroll
    for (int n = 0; n < 2; ++n) {
      const bf16_t* Wc = Wbig + ((long)g*2048 + cg0 + wn*32 + n*16 + lr) * 256;
      f32x4 aX = {0.f,0.f,0.f,0.f};
      f32x4 aH = {0.f,0.f,0.f,0.f};
      f32x4 aC = {0.f,0.f,0.f,0.f};
      {  // X scale: kstep0 (hi*hi + hi*lo + lo*hi)
        bf16x8 zh = *(const bf16x8*)(Zr + 0*32 + lq*8);
        bf16x8 zl = *(const bf16x8*)(Zr + 128 + 0*32 + lq*8);
        bf16x8 wh = *(const bf16x8*)(Wc + 0*32 + lq*8);
        bf16x8 wl = *(const bf16x8*)(Wc + 128 + 0*32 + lq*8);
        aX = __builtin_amdgcn_mfma_f32_16x16x32_bf16(zh, wh, aX, 0,0,0);
        aX = __builtin_amdgcn_mfma_f32_16x16x32_bf16(zh, wl, aX, 0,0,0);
        aX = __builtin_amdgcn_mfma_f32_16x16x32_bf16(zl, wh, aX, 0,0,0);
      }
      {  // H scale: kstep1
        bf16x8 zh = *(const bf16x8*)(Zr + 1*32 + lq*8);
        bf16x8 zl = *(const bf16x8*)(Zr + 128 + 1*32 + lq*8);
        bf16x8 wh = *(const bf16x8*)(Wc + 1*32 + lq*8);
        bf16x8 wl = *(const bf16x8*)(Wc + 128 + 1*32 + lq*8);
        aH = __builtin_amdgcn_mfma_f32_16x16x32_bf16(zh, wh, aH, 0,0,0);
        aH = __builtin_amdgcn_mfma_f32_16x16x32_bf16(zh, wl, aH, 0,0,0);
        aH = __builtin_amdgcn_mfma_f32_16x16x32_bf16(zl, wh, aH, 0,0,0);
      }
      {  // C offset: ksteps 2,3
        bf16x8 zh = *(const bf16x8*)(Zr + 2*32 + lq*8);
        bf16x8 zl = *(const bf16x8*)(Zr + 128 + 2*32 + lq*8);
        bf16x8 wh = *(const bf16x8*)(Wc + 2*32 + lq*8);
        bf16x8 wl = *(const bf16x8*)(Wc + 128 + 2*32 + lq*8);
        aC = __builtin_amdgcn_mfma_f32_16x16x32_bf16(zh, wh, aC, 0,0,0);
        aC = __builtin_amdgcn_mfma_f32_16x16x32_bf16(zh, wl, aC, 0,0,0);
        aC = __builtin_amdgcn_mfma_f32_16x16x32_bf16(zl, wh, aC, 0,0,0);
        zh = *(const bf16x8*)(Zr + 3*32 + lq*8);
        zl = *(const bf16x8*)(Zr + 128 + 3*32 + lq*8);
        wh = *(const bf16x8*)(Wc + 3*32 + lq*8);
        wl = *(const bf16x8*)(Wc + 128 + 3*32 + lq*8);
        aC = __builtin_amdgcn_mfma_f32_16x16x32_bf16(zh, wh, aC, 0,0,0);
        aC = __builtin_amdgcn_mfma_f32_16x16x32_bf16(zh, wl, aC, 0,0,0);
        aC = __builtin_amdgcn_mfma_f32_16x16x32_bf16(zl, wh, aC, 0,0,0);
      }
      #pragma unroll
      for (int i = 0; i < 4; ++i) {
        long row = tm + wm*64 + m*16 + lq*4 + i;
        long col = (long)tn + wn*32 + n*16 + lr;
        gates[row*8192 + col] = aX[i]*accX[m][n][i] + aH[i]*accH[m][n][i] + aC[i];
      }
    }
  }
}

// ---------------- hyper LSTM cell: 1 wave per batch row; sums 5 split-K partials ----------------
__global__ __launch_bounds__(64) void hyper_cell_k(const float* __restrict__ hcat_part,
                                                   const float* __restrict__ tc,
                                                   const float* __restrict__ h_bias,
                                                   const float* __restrict__ hg, const float* __restrict__ hb,
                                                   const float* __restrict__ hcg, const float* __restrict__ hcb,
                                                   float* __restrict__ out, float* __restrict__ hout) {
  const int b = blockIdx.x, l = threadIdx.x;
  const int u0 = 2 * l;
  float v[4][2], nv[4][2];
  #pragma unroll
  for (int g = 0; g < 4; ++g)
    #pragma unroll
    for (int p = 0; p < 2; ++p) {
      long idx = (long)b*512 + g*128 + u0 + p;
      float s = h_bias[g*128 + u0 + p];
      #pragma unroll
      for (int z = 0; z < 5; ++z) s += hcat_part[z*2097152L + idx];
      v[g][p] = s;
    }
  #pragma unroll
  for (int g = 0; g < 4; ++g) {
    float s = v[g][0] + v[g][1];
    float q = v[g][0]*v[g][0] + v[g][1]*v[g][1];
    #pragma unroll
    for (int m = 32; m >= 1; m >>= 1) { s += __shfl_xor(s, m); q += __shfl_xor(q, m); }
    float mean = s * (1.0f/128.0f);
    float inv = rsqrtf(q * (1.0f/128.0f) - mean*mean + EPS);
    #pragma unroll
    for (int p = 0; p < 2; ++p)
      nv[g][p] = (v[g][p] - mean) * inv * hg[g*128 + u0 + p] + hb[g*128 + u0 + p];
  }
  float nc[2], oo[2];
  #pragma unroll
  for (int p = 0; p < 2; ++p) {
    float ii = sigmoidf_(nv[0][p]);
    float jj = tanhf(nv[1][p]);
    float ff = sigmoidf_(nv[2][p] + 1.0f);
    oo[p] = sigmoidf_(nv[3][p]);
    float hc = tc[(long)b*2176 + 2048 + u0 + p];
    nc[p] = hc * ff + ii * jj;
  }
  float s = nc[0] + nc[1], q = nc[0]*nc[0] + nc[1]*nc[1];
  #pragma unroll
  for (int m = 32; m >= 1; m >>= 1) { s += __shfl_xor(s, m); q += __shfl_xor(q, m); }
  float mean = s * (1.0f/128.0f);
  float inv = rsqrtf(q * (1.0f/128.0f) - mean*mean + EPS);
  #pragma unroll
  for (int p = 0; p < 2; ++p) {
    float nh = tanhf((nc[p] - mean) * inv * hcg[u0 + p] + hcb[u0 + p]) * oo[p];
    out[OUT1 + (long)b*2176 + 2048 + u0 + p] = nc[p];
    out[OUT2 + (long)b*2176 + 2048 + u0 + p] = nh;
    hout[(long)b*128 + u0 + p] = nh;
  }
}

// ---------------- zhyper: compute zw/zb dots and write Zbig[4][4096][2][128] bf16 hi/lo ----------------
__global__ __launch_bounds__(192) void zhyper_k(const float* __restrict__ hout,
                                                const float* __restrict__ zwW, const float* __restrict__ zbias,
                                                const float* __restrict__ zbW,
                                                bf16_t* __restrict__ Zbig) {
  const int b = blockIdx.x, t = threadIdx.x;
  __shared__ float ho[128];
  if (t < 128) ho[t] = hout[(long)b*128 + t];
  if (t < 128) {  // zero-fill pad segs 1,3 for all 4 gates (hi+lo)
    int zg = t >> 5, zs = 1 + 2*((t >> 4) & 1), ze = t & 15;
    long zbase = ((long)(zg*4096) + b)*256 + zs*16 + ze;
    Zbig[zbase] = (bf16_t)0.f; Zbig[zbase + 128] = (bf16_t)0.f;
  }
  __syncthreads();
  const int k = t >> 4, e = t & 15;
  float a = 0.f, a2 = 0.f;
  const float* wp = zwW + (long)k*2048 + e;
  const float* bp = zbW + (long)k*2048 + e;
  #pragma unroll 8
  for (int u = 0; u < 128; ++u) { float h = ho[u]; a += h * wp[u*16]; a2 += h * bp[u*16]; }
  a += zbias[k*16 + e];
  const int g = k & 3, kk = k >> 2;
  const int segA = kk*2;      // 0,2,4
  const int segB = kk + 5;    // 5,6,7
  long baseg = ((long)(g*4096) + b)*256;
  bf16_t ah = (bf16_t)a;
  Zbig[baseg + segA*16 + e]       = ah;
  Zbig[baseg + 128 + segA*16 + e] = (bf16_t)(a - (float)ah);
  bf16_t bh = (bf16_t)a2;
  Zbig[baseg + segB*16 + e]       = bh;
  Zbig[baseg + 128 + segB*16 + e] = (bf16_t)(a2 - (float)bh);
}

// ---------------- wbig: pack weights -> Wbig[4][2048][2][128] bf16 hi/lo (bias folded at seg 4) ----------------
__global__ __launch_bounds__(256) void wbig_k(const float* __restrict__ ww,
                                              const float* __restrict__ bw,
                                              const float* __restrict__ bias,
                                              bf16_t* __restrict__ Wbig) {
  int idx = blockIdx.x * 256 + threadIdx.x;   // 4*2048*16 = 131072 chunks of 8 k
  int c = idx & 15;
  int j = (idx >> 4) & 2047;
  int g = idx >> 15;
  int k0 = c * 8, seg = k0 >> 4, e0 = k0 & 15;
  float v[8];
  for (int u = 0; u < 8; ++u) v[u] = 0.f;
  if (seg == 0) {
    for (int u = 0; u < 8; ++u) v[u] = ww[(long)((g*16) + e0 + u)*2048 + j];
  } else if (seg == 2) {
    for (int u = 0; u < 8; ++u) v[u] = ww[(long)(((4+g)*16) + e0 + u)*2048 + j];
  } else if (seg == 4) {
    float bc = bias[g*2048 + j];
    for (int u = 0; u < 8; ++u) v[u] = ww[(long)(((8+g)*16) + e0 + u)*2048 + j] * bc;
  } else if (seg == 5) {
    for (int u = 0; u < 8; ++u) v[u] = bw[(long)((g*16) + e0 + u)*2048 + j];
  } else if (seg == 6) {
    for (int u = 0; u < 8; ++u) v[u] = bw[(long)(((4+g)*16) + e0 + u)*2048 + j];
  } else if (seg == 7) {
    for (int u = 0; u < 8; ++u) v[u] = bw[(long)(((8+g)*16) + e0 + u)*2048 + j];
  }
  bf16x8 hi, lo;
  for (int u = 0; u < 8; ++u) {
    bf16_t h = (bf16_t)v[u];
    hi[u] = h; lo[u] = (bf16_t)(v[u] - (float)h);
  }
  long base = ((long)(g*2048) + j)*256 + k0;
  *(bf16x8*)(Wbig + base)       = hi;
  *(bf16x8*)(Wbig + base + 128) = lo;
}

// ---------------- M2: main cell — 4 gate-LNs, LSTM update, c-LN, outputs ----------------
__global__ __launch_bounds__(256) void cell_main_k(const float* __restrict__ gates,
                                                   const float* __restrict__ tc,
                                                   const float* __restrict__ lng, const float* __restrict__ lnb,
                                                   const float* __restrict__ lcg, const float* __restrict__ lcb,
                                                   float* __restrict__ out) {
  const int b = blockIdx.x, t = threadIdx.x;
  const int wave = t >> 6, lane = t & 63;
  const int j0 = t * 8;
  float gv[4][8], s[4], q[4];
  #pragma unroll
  for (int g = 0; g < 4; ++g) {
    float4 v0 = *(const float4*)(gates + (long)b*8192 + g*2048 + j0);
    float4 v1 = *(const float4*)(gates + (long)b*8192 + g*2048 + j0 + 4);
    gv[g][0]=v0.x; gv[g][1]=v0.y; gv[g][2]=v0.z; gv[g][3]=v0.w;
    gv[g][4]=v1.x; gv[g][5]=v1.y; gv[g][6]=v1.z; gv[g][7]=v1.w;
    float ls = 0.f, lq = 0.f;
    #pragma unroll
    for (int u = 0; u < 8; ++u) { float f = gv[g][u]; ls += f; lq += f*f; }
    s[g] = ls; q[g] = lq;
  }
  #pragma unroll
  for (int g = 0; g < 4; ++g)
    #pragma unroll
    for (int m = 32; m >= 1; m >>= 1) { s[g] += __shfl_xor(s[g], m); q[g] += __shfl_xor(q[g], m); }
  __shared__ float red[4][4][2];
  if (lane == 0) {
    #pragma unroll
    for (int g = 0; g < 4; ++g) { red[g][wave][0] = s[g]; red[g][wave][1] = q[g]; }
  }
  __syncthreads();
  float mean[4], inv[4];
  #pragma unroll
  for (int g = 0; g < 4; ++g) {
    float S = red[g][0][0] + red[g][1][0] + red[g][2][0] + red[g][3][0];
    float Q = red[g][0][1] + red[g][1][1] + red[g][2][1] + red[g][3][1];
    float m = S * (1.0f/2048.0f);
    mean[g] = m; inv[g] = rsqrtf(Q * (1.0f/2048.0f) - m*m + EPS);
  }
  float nc[8], oo[8];
  const float* cb = tc + (long)b*2176;
  #pragma unroll
  for (int u = 0; u < 8; ++u) {
    int j = j0 + u;
    float iv = (gv[0][u] - mean[0]) * inv[0] * lng[j]        + lnb[j];
    float jv = (gv[1][u] - mean[1]) * inv[1] * lng[2048 + j] + lnb[2048 + j];
    float fv = (gv[2][u] - mean[2]) * inv[2] * lng[4096 + j] + lnb[4096 + j];
    float ov = (gv[3][u] - mean[3]) * inv[3] * lng[6144 + j] + lnb[6144 + j];
    nc[u] = cb[j] * sigmoidf_(fv + 1.0f) + sigmoidf_(iv) * tanhf(jv);
    oo[u] = sigmoidf_(ov);
  }
  float s2 = 0.f, q2 = 0.f;
  #pragma unroll
  for (int u = 0; u < 8; ++u) { s2 += nc[u]; q2 += nc[u]*nc[u]; }
  #pragma unroll
  for (int m = 32; m >= 1; m >>= 1) { s2 += __shfl_xor(s2, m); q2 += __shfl_xor(q2, m); }
  __syncthreads();
  if (lane == 0) { red[0][wave][0] = s2; red[0][wave][1] = q2; }
  __syncthreads();
  float S2 = red[0][0][0] + red[0][1][0] + red[0][2][0] + red[0][3][0];
  float Q2 = red[0][0][1] + red[0][1][1] + red[0][2][1] + red[0][3][1];
  float mc = S2 * (1.0f/2048.0f);
  float ic = rsqrtf(Q2 * (1.0f/2048.0f) - mc*mc + EPS);
  float nh[8];
  #pragma unroll
  for (int u = 0; u < 8; ++u)
    nh[u] = tanhf((nc[u] - mc) * ic * lcg[j0 + u] + lcb[j0 + u]) * oo[u];
  float4 h0 = make_float4(nh[0], nh[1], nh[2], nh[3]);
  float4 h1 = make_float4(nh[4], nh[5], nh[6], nh[7]);
  float4 c0 = make_float4(nc[0], nc[1], nc[2], nc[3]);
  float4 c1 = make_float4(nc[4], nc[5], nc[6], nc[7]);
  *(float4*)(out + (long)b*2048 + j0)            = h0;
  *(float4*)(out + (long)b*2048 + j0 + 4)        = h1;
  *(float4*)(out + OUT1 + (long)b*2176 + j0)     = c0;
  *(float4*)(out + OUT1 + (long)b*2176 + j0 + 4) = c1;
  *(float4*)(out + OUT2 + (long)b*2176 + j0)     = h0;
  *(float4*)(out + OUT2 + (long)b*2176 + j0 + 4) = h1;
}

extern "C" void kernel_launch(void* const* d_in, const int* in_sizes, int n_in,
                              void* d_out, int out_size, void* d_ws, size_t ws_size,
                              hipStream_t stream) {
  const float* x      = (const float*)d_in[0];
  const float* tc     = (const float*)d_in[1];
  const float* th     = (const float*)d_in[2];
  const float* W_xh   = (const float*)d_in[3];
  const float* W_hh   = (const float*)d_in[4];
  const float* bias   = (const float*)d_in[5];
  const float* ln_g   = (const float*)d_in[6];
  const float* ln_b   = (const float*)d_in[7];
  const float* lnc_g  = (const float*)d_in[8];
  const float* lnc_b  = (const float*)d_in[9];
  const float* hW_xh  = (const float*)d_in[10];
  const float* hW_hh  = (const float*)d_in[11];
  const float* h_bias = (const float*)d_in[12];
  const float* h_ln_g = (const float*)d_in[13];
  const float* h_ln_b = (const float*)d_in[14];
  const float* h_lnc_g= (const float*)d_in[15];
  const float* h_lnc_b= (const float*)d_in[16];
  const float* hyp_zw = (const float*)d_in[17];
  const float* hyp_zb = (const float*)d_in[18];
  const float* hyp_ww = (const float*)d_in[19];
  const float* hyp_zbw= (const float*)d_in[20];
  const float* hyp_bw = (const float*)d_in[21];
  float* out = (float*)d_out;

  // Workspace layout. Total ~258 MB.
  char* w = (char*)d_ws;
  bf16_t* A        = (bf16_t*)w;  w += 4096L*3200*2;   //  26,214,400
  bf16_t* WtALL    = (bf16_t*)w;  w += 8192L*3072*2;   //  50,331,648
  bf16_t* WtCAT    = (bf16_t*)w;  w += 512L*3200*2;    //   3,276,800
  float*  hcat_part= (float*)w;   w += 5L*4096*512*4;  //  41,943,040
  float*  hout     = (float*)w;   w += 4096L*128*4;    //   2,097,152
  bf16_t* Zbig     = (bf16_t*)w;  w += 4L*4096*256*2;  //   8,388,608
  bf16_t* Wbig     = (bf16_t*)w;  w += 4L*2048*256*2;  //   4,194,304
  float*  gates    = (float*)w;   w += 4096L*8192*4;   // 134,217,728

  build_A_k<<<2048, 256, 0, stream>>>(x, th, A);
  transpose_conv_k<<<dim3(256, 96),  dim3(32, 8), 0, stream>>>(W_xh, 1024, W_hh, 3072, 8192, WtALL);
  transpose_conv_k<<<dim3(16, 100),  dim3(32, 8), 0, stream>>>(hW_xh, 3072, hW_hh, 3200, 512, WtCAT);
  gemm_bf16_k<float><<<dim3(4, 32, 5), 256, 0, stream>>>(A, 3200, WtCAT, 3200, hcat_part, 512, 640, 4096L*512);
  hyper_cell_k<<<4096, 64, 0, stream>>>(hcat_part, tc, h_bias, h_ln_g, h_ln_b, h_lnc_g, h_lnc_b, out, hout);
  zhyper_k<<<4096, 192, 0, stream>>>(hout, hyp_zw, hyp_zb, hyp_zbw, Zbig);
  wbig_k<<<512, 256, 0, stream>>>(hyp_ww, hyp_bw, bias, Wbig);
  gemm_fused2_k<<<dim3(64, 32), 512, 0, stream>>>(A, WtALL, Zbig, Wbig, gates);
  cell_main_k<<<4096, 256, 0, stream>>>(gates, tc, ln_g, ln_b, lnc_g, lnc_b, out);
}

// Round 15
// 659.574 us; speedup vs baseline: 1.3003x; 1.3003x over previous
//
#include <hip/hip_runtime.h>

typedef __bf16 bf16_t;
typedef __attribute__((ext_vector_type(8))) __bf16 bf16x8;
typedef __attribute__((ext_vector_type(4))) __bf16 bf16x4;
typedef __attribute__((ext_vector_type(4))) float f32x4;

#define EPS 1e-3f
#define OUT1 (4096L*2048)
#define OUT2 (OUT1 + 4096L*2176)

__device__ __forceinline__ float sigmoidf_(float x){ return 1.0f/(1.0f+expf(-x)); }

__device__ __forceinline__ void glds16(const void* g, void* l) {
  __builtin_amdgcn_global_load_lds(
      (__attribute__((address_space(1))) void*)g,
      (__attribute__((address_space(3))) void*)l, 16, 0, 0);
}

// ---------------- build A = [x | h | hyper_h] as bf16, [4096][3200] ----------------
__global__ __launch_bounds__(256) void build_A_k(const float* __restrict__ x,
                                                 const float* __restrict__ th,
                                                 bf16_t* __restrict__ A) {
  const int total = 4096 * 800;  // groups of 4 elements
  for (int i = blockIdx.x * blockDim.x + threadIdx.x; i < total; i += gridDim.x * blockDim.x) {
    int b = i / 800;
    int c4 = (i - b * 800) * 4;
    float4 v;
    if (c4 < 1024)       v = *(const float4*)(x  + (long)b*1024 + c4);
    else if (c4 < 3072)  v = *(const float4*)(th + (long)b*2176 + (c4 - 1024));
    else                 v = *(const float4*)(th + (long)b*2176 + 2048 + (c4 - 3072));
    bf16x4 o = { (bf16_t)v.x, (bf16_t)v.y, (bf16_t)v.z, (bf16_t)v.w };
    *(bf16x4*)(A + (long)i*4) = o;
  }
}

// ---------------- transpose + convert: in fp32 [K][N] (split at K1) -> out bf16 [N][Ktot] ----------------
__global__ __launch_bounds__(256) void transpose_conv_k(const float* __restrict__ in1, int K1,
                                                        const float* __restrict__ in2, int Ktot,
                                                        int N, bf16_t* __restrict__ out) {
  __shared__ float tile[32][33];
  int n0 = blockIdx.x * 32, k0 = blockIdx.y * 32;
  int tx = threadIdx.x, ty = threadIdx.y;  // (32,8)
  #pragma unroll
  for (int r = 0; r < 4; ++r) {
    int k = k0 + ty + r*8;
    float v = (k < K1) ? in1[(long)k*N + n0 + tx] : in2[(long)(k - K1)*N + n0 + tx];
    tile[ty + r*8][tx] = v;
  }
  __syncthreads();
  #pragma unroll
  for (int r = 0; r < 4; ++r) {
    int n = n0 + ty + r*8;
    out[(long)n*Ktot + k0 + tx] = (bf16_t)tile[tx][ty + r*8];
  }
}

// ---------------- bf16 GEMM, split-K via blockIdx.z, 2-phase LDS double-buffer ----------------
template<typename T>
__global__ __launch_bounds__(256) void gemm_bf16_k(const bf16_t* __restrict__ A, int lda,
                                                   const bf16_t* __restrict__ Bt, int ldb,
                                                   T* __restrict__ C, int ldc, int K,
                                                   long coutStride) {
  const int z = blockIdx.z;
  A  += (long)z * K;
  Bt += (long)z * K;
  C  += (long)z * coutStride;
  __shared__ bf16_t sA[2*128*64];
  __shared__ bf16_t sB[2*128*64];
  const int tid = threadIdx.x;
  const int wave = tid >> 6, lane = tid & 63;
  const int tm = blockIdx.y * 128, tn = blockIdx.x * 128;
  const int wm = wave >> 1, wn = wave & 1;
  const int lq = lane >> 4, lr = lane & 15;

  const bf16_t* Ab = A + (long)tm * lda;
  const bf16_t* Bb = Bt + (long)tn * ldb;

  f32x4 acc[4][4];
  #pragma unroll
  for (int m = 0; m < 4; ++m)
    #pragma unroll
    for (int n = 0; n < 4; ++n) { f32x4 zv = {0.f,0.f,0.f,0.f}; acc[m][n] = zv; }

  int rowS[4], kofS[4], ldsoff[4];
  #pragma unroll
  for (int c = 0; c < 4; ++c) {
    int ci = c*256 + tid;
    int row = ci >> 3, kcp = ci & 7;
    int kcl = kcp ^ (row & 7);           // pre-swizzled source chunk
    rowS[c] = row; kofS[c] = kcl * 8;
    ldsoff[c] = (c*256 + wave*64) * 8;   // wave-uniform element offset
  }

#define H_STAGE(BUF, K0)                                                          \
  { const int k0 = (K0);                                                          \
    _Pragma("unroll")                                                             \
    for (int c = 0; c < 4; ++c) {                                                 \
      glds16(Ab + (long)rowS[c]*lda + k0 + kofS[c], sA + (BUF)*8192 + ldsoff[c]); \
      glds16(Bb + (long)rowS[c]*ldb + k0 + kofS[c], sB + (BUF)*8192 + ldsoff[c]); \
    } }

  const int nk = K >> 6;
  int cur = 0;
  H_STAGE(0, 0)
  __syncthreads();
  for (int kt = 0; kt < nk; ++kt) {
    if (kt + 1 < nk) H_STAGE(cur ^ 1, (kt + 1) << 6)
    const bf16_t* aB = sA + cur*8192;
    const bf16_t* bB = sB + cur*8192;
    #pragma unroll
    for (int kk = 0; kk < 64; kk += 32) {
      const int kc = (kk >> 3) + lq;
      bf16x8 af[4], bf[4];
      #pragma unroll
      for (int m = 0; m < 4; ++m) {
        int row = wm*64 + m*16 + lr;
        af[m] = *(const bf16x8*)(aB + row*64 + ((kc ^ (row & 7)) << 3));
      }
      #pragma unroll
      for (int n = 0; n < 4; ++n) {
        int row = wn*64 + n*16 + lr;
        bf[n] = *(const bf16x8*)(bB + row*64 + ((kc ^ (row & 7)) << 3));
      }
      #pragma unroll
      for (int m = 0; m < 4; ++m)
        #pragma unroll
        for (int n = 0; n < 4; ++n)
          acc[m][n] = __builtin_amdgcn_mfma_f32_16x16x32_bf16(af[m], bf[n], acc[m][n], 0, 0, 0);
    }
    __syncthreads();
    cur ^= 1;
  }
#undef H_STAGE

  // epilogue: C/D layout col=lane&15, row=(lane>>4)*4+i
  #pragma unroll
  for (int m = 0; m < 4; ++m)
    #pragma unroll
    for (int i = 0; i < 4; ++i) {
      long row = tm + wm*64 + m*16 + lq*4 + i;
      #pragma unroll
      for (int n = 0; n < 4; ++n) {
        int col = tn + wn*64 + n*16 + lr;
        C[row*ldc + col] = (T)acc[m][n][i];
      }
    }
}

// ---------------- fused dual-acc GEMM + modulation epilogue, 8-wave 128x128 tile ----------------
// Counted-vmcnt pipeline (T4): tiles t,t+1 always in flight; vmcnt(4) waits ONLY the
// oldest 4 loads (tile t); raw s_barrier (no vmcnt(0) drain in the main loop).
// Iter t: vmcnt(4) -> bar -> compute buf[t&1] -> bar -> STAGE(buf[t&1], t+2).
// Overwrite of buf[t&1] occurs only after the post-compute barrier => race-free.
// [R14 lesson: 3-buffer single-barrier stage-early variant REGRESSED (VGPR 120,
//  96KB LDS, 1 blk/CU, 560us) — this 2-buffer form (VGPR 64, 43% occ, 361us) is
//  the measured best of 5 schedule variants on this structure.]
__global__ __launch_bounds__(512, 4) void gemm_fused2_k(const bf16_t* __restrict__ A,
                                                        const bf16_t* __restrict__ Wt,   // [8192][3072]
                                                        const bf16_t* __restrict__ Zbig,
                                                        const bf16_t* __restrict__ Wbig,
                                                        float* __restrict__ gates) {
  __shared__ bf16_t sA[2*128*64];
  __shared__ bf16_t sB[2*128*64];
  const int tid = threadIdx.x;
  const int wave = tid >> 6, lane = tid & 63;
  const int tm = blockIdx.y * 128, tn = blockIdx.x * 128;
  const int wm = wave >> 2, wn = wave & 3;
  const int lq = lane >> 4, lr = lane & 15;

  const bf16_t* Ab = A  + (long)tm * 3200;
  const bf16_t* Bb = Wt + (long)tn * 3072;

  f32x4 accX[4][2], accH[4][2];
  #pragma unroll
  for (int m = 0; m < 4; ++m)
    #pragma unroll
    for (int n = 0; n < 2; ++n) { f32x4 zv = {0.f,0.f,0.f,0.f}; accX[m][n] = zv; accH[m][n] = zv; }

  int rowS[2], kofS[2], ldsoff[2];
  #pragma unroll
  for (int c = 0; c < 2; ++c) {
    int ci = c*512 + tid;
    int row = ci >> 3, kcp = ci & 7;
    int kcl = kcp ^ (row & 7);           // pre-swizzled source chunk
    rowS[c] = row; kofS[c] = kcl * 8;
    ldsoff[c] = (c*512 + wave*64) * 8;   // wave-uniform element offset
  }

#define F_STAGE(BUF, K0)                                                            \
  { const int k0 = (K0);                                                            \
    _Pragma("unroll")                                                               \
    for (int c = 0; c < 2; ++c) {                                                   \
      glds16(Ab + (long)rowS[c]*3200 + k0 + kofS[c], sA + (BUF)*8192 + ldsoff[c]);  \
      glds16(Bb + (long)rowS[c]*3072 + k0 + kofS[c], sB + (BUF)*8192 + ldsoff[c]);  \
    } }

#define F_COMPUTE(BUF, ACC)                                                         \
  { const bf16_t* aB = sA + (BUF)*8192;                                             \
    const bf16_t* bB = sB + (BUF)*8192;                                             \
    _Pragma("unroll")                                                               \
    for (int kk = 0; kk < 64; kk += 32) {                                           \
      const int kc = (kk >> 3) + lq;                                                \
      bf16x8 af[4], bfr[2];                                                         \
      _Pragma("unroll")                                                             \
      for (int m = 0; m < 4; ++m) {                                                 \
        int row = wm*64 + m*16 + lr;                                                \
        af[m] = *(const bf16x8*)(aB + row*64 + ((kc ^ (row & 7)) << 3));            \
      }                                                                             \
      _Pragma("unroll")                                                             \
      for (int n = 0; n < 2; ++n) {                                                 \
        int row = wn*32 + n*16 + lr;                                                \
        bfr[n] = *(const bf16x8*)(bB + row*64 + ((kc ^ (row & 7)) << 3));           \
      }                                                                             \
      _Pragma("unroll")                                                             \
      for (int m = 0; m < 4; ++m)                                                   \
        _Pragma("unroll")                                                           \
        for (int n = 0; n < 2; ++n)                                                 \
          ACC[m][n] = __builtin_amdgcn_mfma_f32_16x16x32_bf16(af[m], bfr[n], ACC[m][n], 0, 0, 0); \
    } }

#define WAITV4 asm volatile("s_waitcnt vmcnt(4)" ::: "memory")
#define WAITV0 asm volatile("s_waitcnt vmcnt(0)" ::: "memory")
#define BAR()  __builtin_amdgcn_s_barrier()

  int cur = 0;
  F_STAGE(0, 0)
  F_STAGE(1, 64)
  // X phase: kt = 0..15 (kt+2 <= 17 < 48, always stage)
  for (int kt = 0; kt < 16; ++kt) {
    WAITV4;                      // tile kt's 4 loads done (oldest of 8)
    BAR();
    F_COMPUTE(cur, accX)
    BAR();
    F_STAGE(cur, (kt + 2) << 6)  // overwrite buf read this iter (safe after barrier)
    cur ^= 1;
  }
  // H phase: kt = 16..47
  for (int kt = 16; kt < 48; ++kt) {
    if (kt < 47) { WAITV4; } else { WAITV0; }
    BAR();
    F_COMPUTE(cur, accH)
    BAR();
    if (kt + 2 < 48) F_STAGE(cur, (kt + 2) << 6)
    cur ^= 1;
  }
#undef F_STAGE
#undef F_COMPUTE
#undef WAITV4
#undef WAITV0
#undef BAR

  // ---- modulation epilogue (Z frags reloaded per-n to cap register liveness) ----
  const int g   = tn >> 11;       // gate index (tile lies within one gate; 256|2048)
  const int cg0 = tn & 2047;      // col offset within gate
  #pragma unroll
  for (int m = 0; m < 4; ++m) {
    const bf16_t* Zr = Zbig + ((long)g*4096 + tm + wm*64 + m*16 + lr) * 256;
    #pragma unroll
    for (int n = 0; n < 2; ++n) {
      const bf16_t* Wc = Wbig + ((long)g*2048 + cg0 + wn*32 + n*16 + lr) * 256;
      f32x4 aX = {0.f,0.f,0.f,0.f};
      f32x4 aH = {0.f,0.f,0.f,0.f};
      f32x4 aC = {0.f,0.f,0.f,0.f};
      {  // X scale: kstep0 (hi*hi + hi*lo + lo*hi)
        bf16x8 zh = *(const bf16x8*)(Zr + 0*32 + lq*8);
        bf16x8 zl = *(const bf16x8*)(Zr + 128 + 0*32 + lq*8);
        bf16x8 wh = *(const bf16x8*)(Wc + 0*32 + lq*8);
        bf16x8 wl = *(const bf16x8*)(Wc + 128 + 0*32 + lq*8);
        aX = __builtin_amdgcn_mfma_f32_16x16x32_bf16(zh, wh, aX, 0,0,0);
        aX = __builtin_amdgcn_mfma_f32_16x16x32_bf16(zh, wl, aX, 0,0,0);
        aX = __builtin_amdgcn_mfma_f32_16x16x32_bf16(zl, wh, aX, 0,0,0);
      }
      {  // H scale: kstep1
        bf16x8 zh = *(const bf16x8*)(Zr + 1*32 + lq*8);
        bf16x8 zl = *(const bf16x8*)(Zr + 128 + 1*32 + lq*8);
        bf16x8 wh = *(const bf16x8*)(Wc + 1*32 + lq*8);
        bf16x8 wl = *(const bf16x8*)(Wc + 128 + 1*32 + lq*8);
        aH = __builtin_amdgcn_mfma_f32_16x16x32_bf16(zh, wh, aH, 0,0,0);
        aH = __builtin_amdgcn_mfma_f32_16x16x32_bf16(zh, wl, aH, 0,0,0);
        aH = __builtin_amdgcn_mfma_f32_16x16x32_bf16(zl, wh, aH, 0,0,0);
      }
      {  // C offset: ksteps 2,3
        bf16x8 zh = *(const bf16x8*)(Zr + 2*32 + lq*8);
        bf16x8 zl = *(const bf16x8*)(Zr + 128 + 2*32 + lq*8);
        bf16x8 wh = *(const bf16x8*)(Wc + 2*32 + lq*8);
        bf16x8 wl = *(const bf16x8*)(Wc + 128 + 2*32 + lq*8);
        aC = __builtin_amdgcn_mfma_f32_16x16x32_bf16(zh, wh, aC, 0,0,0);
        aC = __builtin_amdgcn_mfma_f32_16x16x32_bf16(zh, wl, aC, 0,0,0);
        aC = __builtin_amdgcn_mfma_f32_16x16x32_bf16(zl, wh, aC, 0,0,0);
        zh = *(const bf16x8*)(Zr + 3*32 + lq*8);
        zl = *(const bf16x8*)(Zr + 128 + 3*32 + lq*8);
        wh = *(const bf16x8*)(Wc + 3*32 + lq*8);
        wl = *(const bf16x8*)(Wc + 128 + 3*32 + lq*8);
        aC = __builtin_amdgcn_mfma_f32_16x16x32_bf16(zh, wh, aC, 0,0,0);
        aC = __builtin_amdgcn_mfma_f32_16x16x32_bf16(zh, wl, aC, 0,0,0);
        aC = __builtin_amdgcn_mfma_f32_16x16x32_bf16(zl, wh, aC, 0,0,0);
      }
      #pragma unroll
      for (int i = 0; i < 4; ++i) {
        long row = tm + wm*64 + m*16 + lq*4 + i;
        long col = (long)tn + wn*32 + n*16 + lr;
        gates[row*8192 + col] = aX[i]*accX[m][n][i] + aH[i]*accH[m][n][i] + aC[i];
      }
    }
  }
}

// ---------------- hyper LSTM cell: 1 wave per batch row; sums 5 split-K partials ----------------
__global__ __launch_bounds__(64) void hyper_cell_k(const float* __restrict__ hcat_part,
                                                   const float* __restrict__ tc,
                                                   const float* __restrict__ h_bias,
                                                   const float* __restrict__ hg, const float* __restrict__ hb,
                                                   const float* __restrict__ hcg, const float* __restrict__ hcb,
                                                   float* __restrict__ out, float* __restrict__ hout) {
  const int b = blockIdx.x, l = threadIdx.x;
  const int u0 = 2 * l;
  float v[4][2], nv[4][2];
  #pragma unroll
  for (int g = 0; g < 4; ++g)
    #pragma unroll
    for (int p = 0; p < 2; ++p) {
      long idx = (long)b*512 + g*128 + u0 + p;
      float s = h_bias[g*128 + u0 + p];
      #pragma unroll
      for (int z = 0; z < 5; ++z) s += hcat_part[z*2097152L + idx];
      v[g][p] = s;
    }
  #pragma unroll
  for (int g = 0; g < 4; ++g) {
    float s = v[g][0] + v[g][1];
    float q = v[g][0]*v[g][0] + v[g][1]*v[g][1];
    #pragma unroll
    for (int m = 32; m >= 1; m >>= 1) { s += __shfl_xor(s, m); q += __shfl_xor(q, m); }
    float mean = s * (1.0f/128.0f);
    float inv = rsqrtf(q * (1.0f/128.0f) - mean*mean + EPS);
    #pragma unroll
    for (int p = 0; p < 2; ++p)
      nv[g][p] = (v[g][p] - mean) * inv * hg[g*128 + u0 + p] + hb[g*128 + u0 + p];
  }
  float nc[2], oo[2];
  #pragma unroll
  for (int p = 0; p < 2; ++p) {
    float ii = sigmoidf_(nv[0][p]);
    float jj = tanhf(nv[1][p]);
    float ff = sigmoidf_(nv[2][p] + 1.0f);
    oo[p] = sigmoidf_(nv[3][p]);
    float hc = tc[(long)b*2176 + 2048 + u0 + p];
    nc[p] = hc * ff + ii * jj;
  }
  float s = nc[0] + nc[1], q = nc[0]*nc[0] + nc[1]*nc[1];
  #pragma unroll
  for (int m = 32; m >= 1; m >>= 1) { s += __shfl_xor(s, m); q += __shfl_xor(q, m); }
  float mean = s * (1.0f/128.0f);
  float inv = rsqrtf(q * (1.0f/128.0f) - mean*mean + EPS);
  #pragma unroll
  for (int p = 0; p < 2; ++p) {
    float nh = tanhf((nc[p] - mean) * inv * hcg[u0 + p] + hcb[u0 + p]) * oo[p];
    out[OUT1 + (long)b*2176 + 2048 + u0 + p] = nc[p];
    out[OUT2 + (long)b*2176 + 2048 + u0 + p] = nh;
    hout[(long)b*128 + u0 + p] = nh;
  }
}

// ---------------- zhyper: compute zw/zb dots and write Zbig[4][4096][2][128] bf16 hi/lo ----------------
__global__ __launch_bounds__(192) void zhyper_k(const float* __restrict__ hout,
                                                const float* __restrict__ zwW, const float* __restrict__ zbias,
                                                const float* __restrict__ zbW,
                                                bf16_t* __restrict__ Zbig) {
  const int b = blockIdx.x, t = threadIdx.x;
  __shared__ float ho[128];
  if (t < 128) ho[t] = hout[(long)b*128 + t];
  if (t < 128) {  // zero-fill pad segs 1,3 for all 4 gates (hi+lo)
    int zg = t >> 5, zs = 1 + 2*((t >> 4) & 1), ze = t & 15;
    long zbase = ((long)(zg*4096) + b)*256 + zs*16 + ze;
    Zbig[zbase] = (bf16_t)0.f; Zbig[zbase + 128] = (bf16_t)0.f;
  }
  __syncthreads();
  const int k = t >> 4, e = t & 15;
  float a = 0.f, a2 = 0.f;
  const float* wp = zwW + (long)k*2048 + e;
  const float* bp = zbW + (long)k*2048 + e;
  #pragma unroll 8
  for (int u = 0; u < 128; ++u) { float h = ho[u]; a += h * wp[u*16]; a2 += h * bp[u*16]; }
  a += zbias[k*16 + e];
  const int g = k & 3, kk = k >> 2;
  const int segA = kk*2;      // 0,2,4
  const int segB = kk + 5;    // 5,6,7
  long baseg = ((long)(g*4096) + b)*256;
  bf16_t ah = (bf16_t)a;
  Zbig[baseg + segA*16 + e]       = ah;
  Zbig[baseg + 128 + segA*16 + e] = (bf16_t)(a - (float)ah);
  bf16_t bh = (bf16_t)a2;
  Zbig[baseg + segB*16 + e]       = bh;
  Zbig[baseg + 128 + segB*16 + e] = (bf16_t)(a2 - (float)bh);
}

// ---------------- wbig: pack weights -> Wbig[4][2048][2][128] bf16 hi/lo (bias folded at seg 4) ----------------
__global__ __launch_bounds__(256) void wbig_k(const float* __restrict__ ww,
                                              const float* __restrict__ bw,
                                              const float* __restrict__ bias,
                                              bf16_t* __restrict__ Wbig) {
  int idx = blockIdx.x * 256 + threadIdx.x;   // 4*2048*16 = 131072 chunks of 8 k
  int c = idx & 15;
  int j = (idx >> 4) & 2047;
  int g = idx >> 15;
  int k0 = c * 8, seg = k0 >> 4, e0 = k0 & 15;
  float v[8];
  for (int u = 0; u < 8; ++u) v[u] = 0.f;
  if (seg == 0) {
    for (int u = 0; u < 8; ++u) v[u] = ww[(long)((g*16) + e0 + u)*2048 + j];
  } else if (seg == 2) {
    for (int u = 0; u < 8; ++u) v[u] = ww[(long)(((4+g)*16) + e0 + u)*2048 + j];
  } else if (seg == 4) {
    float bc = bias[g*2048 + j];
    for (int u = 0; u < 8; ++u) v[u] = ww[(long)(((8+g)*16) + e0 + u)*2048 + j] * bc;
  } else if (seg == 5) {
    for (int u = 0; u < 8; ++u) v[u] = bw[(long)((g*16) + e0 + u)*2048 + j];
  } else if (seg == 6) {
    for (int u = 0; u < 8; ++u) v[u] = bw[(long)(((4+g)*16) + e0 + u)*2048 + j];
  } else if (seg == 7) {
    for (int u = 0; u < 8; ++u) v[u] = bw[(long)(((8+g)*16) + e0 + u)*2048 + j];
  }
  bf16x8 hi, lo;
  for (int u = 0; u < 8; ++u) {
    bf16_t h = (bf16_t)v[u];
    hi[u] = h; lo[u] = (bf16_t)(v[u] - (float)h);
  }
  long base = ((long)(g*2048) + j)*256 + k0;
  *(bf16x8*)(Wbig + base)       = hi;
  *(bf16x8*)(Wbig + base + 128) = lo;
}

// ---------------- M2: main cell — 4 gate-LNs, LSTM update, c-LN, outputs ----------------
__global__ __launch_bounds__(256) void cell_main_k(const float* __restrict__ gates,
                                                   const float* __restrict__ tc,
                                                   const float* __restrict__ lng, const float* __restrict__ lnb,
                                                   const float* __restrict__ lcg, const float* __restrict__ lcb,
                                                   float* __restrict__ out) {
  const int b = blockIdx.x, t = threadIdx.x;
  const int wave = t >> 6, lane = t & 63;
  const int j0 = t * 8;
  float gv[4][8], s[4], q[4];
  #pragma unroll
  for (int g = 0; g < 4; ++g) {
    float4 v0 = *(const float4*)(gates + (long)b*8192 + g*2048 + j0);
    float4 v1 = *(const float4*)(gates + (long)b*8192 + g*2048 + j0 + 4);
    gv[g][0]=v0.x; gv[g][1]=v0.y; gv[g][2]=v0.z; gv[g][3]=v0.w;
    gv[g][4]=v1.x; gv[g][5]=v1.y; gv[g][6]=v1.z; gv[g][7]=v1.w;
    float ls = 0.f, lq = 0.f;
    #pragma unroll
    for (int u = 0; u < 8; ++u) { float f = gv[g][u]; ls += f; lq += f*f; }
    s[g] = ls; q[g] = lq;
  }
  #pragma unroll
  for (int g = 0; g < 4; ++g)
    #pragma unroll
    for (int m = 32; m >= 1; m >>= 1) { s[g] += __shfl_xor(s[g], m); q[g] += __shfl_xor(q[g], m); }
  __shared__ float red[4][4][2];
  if (lane == 0) {
    #pragma unroll
    for (int g = 0; g < 4; ++g) { red[g][wave][0] = s[g]; red[g][wave][1] = q[g]; }
  }
  __syncthreads();
  float mean[4], inv[4];
  #pragma unroll
  for (int g = 0; g < 4; ++g) {
    float S = red[g][0][0] + red[g][1][0] + red[g][2][0] + red[g][3][0];
    float Q = red[g][0][1] + red[g][1][1] + red[g][2][1] + red[g][3][1];
    float m = S * (1.0f/2048.0f);
    mean[g] = m; inv[g] = rsqrtf(Q * (1.0f/2048.0f) - m*m + EPS);
  }
  float nc[8], oo[8];
  const float* cb = tc + (long)b*2176;
  #pragma unroll
  for (int u = 0; u < 8; ++u) {
    int j = j0 + u;
    float iv = (gv[0][u] - mean[0]) * inv[0] * lng[j]        + lnb[j];
    float jv = (gv[1][u] - mean[1]) * inv[1] * lng[2048 + j] + lnb[2048 + j];
    float fv = (gv[2][u] - mean[2]) * inv[2] * lng[4096 + j] + lnb[4096 + j];
    float ov = (gv[3][u] - mean[3]) * inv[3] * lng[6144 + j] + lnb[6144 + j];
    nc[u] = cb[j] * sigmoidf_(fv + 1.0f) + sigmoidf_(iv) * tanhf(jv);
    oo[u] = sigmoidf_(ov);
  }
  float s2 = 0.f, q2 = 0.f;
  #pragma unroll
  for (int u = 0; u < 8; ++u) { s2 += nc[u]; q2 += nc[u]*nc[u]; }
  #pragma unroll
  for (int m = 32; m >= 1; m >>= 1) { s2 += __shfl_xor(s2, m); q2 += __shfl_xor(q2, m); }
  __syncthreads();
  if (lane == 0) { red[0][wave][0] = s2; red[0][wave][1] = q2; }
  __syncthreads();
  float S2 = red[0][0][0] + red[0][1][0] + red[0][2][0] + red[0][3][0];
  float Q2 = red[0][0][1] + red[0][1][1] + red[0][2][1] + red[0][3][1];
  float mc = S2 * (1.0f/2048.0f);
  float ic = rsqrtf(Q2 * (1.0f/2048.0f) - mc*mc + EPS);
  float nh[8];
  #pragma unroll
  for (int u = 0; u < 8; ++u)
    nh[u] = tanhf((nc[u] - mc) * ic * lcg[j0 + u] + lcb[j0 + u]) * oo[u];
  float4 h0 = make_float4(nh[0], nh[1], nh[2], nh[3]);
  float4 h1 = make_float4(nh[4], nh[5], nh[6], nh[7]);
  float4 c0 = make_float4(nc[0], nc[1], nc[2], nc[3]);
  float4 c1 = make_float4(nc[4], nc[5], nc[6], nc[7]);
  *(float4*)(out + (long)b*2048 + j0)            = h0;
  *(float4*)(out + (long)b*2048 + j0 + 4)        = h1;
  *(float4*)(out + OUT1 + (long)b*2176 + j0)     = c0;
  *(float4*)(out + OUT1 + (long)b*2176 + j0 + 4) = c1;
  *(float4*)(out + OUT2 + (long)b*2176 + j0)     = h0;
  *(float4*)(out + OUT2 + (long)b*2176 + j0 + 4) = h1;
}

extern "C" void kernel_launch(void* const* d_in, const int* in_sizes, int n_in,
                              void* d_out, int out_size, void* d_ws, size_t ws_size,
                              hipStream_t stream) {
  const float* x      = (const float*)d_in[0];
  const float* tc     = (const float*)d_in[1];
  const float* th     = (const float*)d_in[2];
  const float* W_xh   = (const float*)d_in[3];
  const float* W_hh   = (const float*)d_in[4];
  const float* bias   = (const float*)d_in[5];
  const float* ln_g   = (const float*)d_in[6];
  const float* ln_b   = (const float*)d_in[7];
  const float* lnc_g  = (const float*)d_in[8];
  const float* lnc_b  = (const float*)d_in[9];
  const float* hW_xh  = (const float*)d_in[10];
  const float* hW_hh  = (const float*)d_in[11];
  const float* h_bias = (const float*)d_in[12];
  const float* h_ln_g = (const float*)d_in[13];
  const float* h_ln_b = (const float*)d_in[14];
  const float* h_lnc_g= (const float*)d_in[15];
  const float* h_lnc_b= (const float*)d_in[16];
  const float* hyp_zw = (const float*)d_in[17];
  const float* hyp_zb = (const float*)d_in[18];
  const float* hyp_ww = (const float*)d_in[19];
  const float* hyp_zbw= (const float*)d_in[20];
  const float* hyp_bw = (const float*)d_in[21];
  float* out = (float*)d_out;

  // Workspace layout. Total ~258 MB.
  char* w = (char*)d_ws;
  bf16_t* A        = (bf16_t*)w;  w += 4096L*3200*2;   //  26,214,400
  bf16_t* WtALL    = (bf16_t*)w;  w += 8192L*3072*2;   //  50,331,648
  bf16_t* WtCAT    = (bf16_t*)w;  w += 512L*3200*2;    //   3,276,800
  float*  hcat_part= (float*)w;   w += 5L*4096*512*4;  //  41,943,040
  float*  hout     = (float*)w;   w += 4096L*128*4;    //   2,097,152
  bf16_t* Zbig     = (bf16_t*)w;  w += 4L*4096*256*2;  //   8,388,608
  bf16_t* Wbig     = (bf16_t*)w;  w += 4L*2048*256*2;  //   4,194,304
  float*  gates    = (float*)w;   w += 4096L*8192*4;   // 134,217,728

  build_A_k<<<2048, 256, 0, stream>>>(x, th, A);
  transpose_conv_k<<<dim3(256, 96),  dim3(32, 8), 0, stream>>>(W_xh, 1024, W_hh, 3072, 8192, WtALL);
  transpose_conv_k<<<dim3(16, 100),  dim3(32, 8), 0, stream>>>(hW_xh, 3072, hW_hh, 3200, 512, WtCAT);
  gemm_bf16_k<float><<<dim3(4, 32, 5), 256, 0, stream>>>(A, 3200, WtCAT, 3200, hcat_part, 512, 640, 4096L*512);
  hyper_cell_k<<<4096, 64, 0, stream>>>(hcat_part, tc, h_bias, h_ln_g, h_ln_b, h_lnc_g, h_lnc_b, out, hout);
  zhyper_k<<<4096, 192, 0, stream>>>(hout, hyp_zw, hyp_zb, hyp_zbw, Zbig);
  wbig_k<<<512, 256, 0, stream>>>(hyp_ww, hyp_bw, bias, Wbig);
  gemm_fused2_k<<<dim3(64, 32), 512, 0, stream>>>(A, WtALL, Zbig, Wbig, gates);
  cell_main_k<<<4096, 256, 0, stream>>>(gates, tc, ln_g, ln_b, lnc_g, lnc_b, out);
}

// Round 16
// 652.975 us; speedup vs baseline: 1.3135x; 1.0101x over previous
//
#include <hip/hip_runtime.h>

typedef __bf16 bf16_t;
typedef __attribute__((ext_vector_type(8))) __bf16 bf16x8;
typedef __attribute__((ext_vector_type(4))) __bf16 bf16x4;
typedef __attribute__((ext_vector_type(4))) float f32x4;

#define EPS 1e-3f
#define OUT1 (4096L*2048)
#define OUT2 (OUT1 + 4096L*2176)

__device__ __forceinline__ float sigmoidf_(float x){ return 1.0f/(1.0f+expf(-x)); }

__device__ __forceinline__ void glds16(const void* g, void* l) {
  __builtin_amdgcn_global_load_lds(
      (__attribute__((address_space(1))) void*)g,
      (__attribute__((address_space(3))) void*)l, 16, 0, 0);
}

// ---------------- build A = [x | h | hyper_h] as bf16, [4096][3200] ----------------
__global__ __launch_bounds__(256) void build_A_k(const float* __restrict__ x,
                                                 const float* __restrict__ th,
                                                 bf16_t* __restrict__ A) {
  const int total = 4096 * 800;  // groups of 4 elements
  for (int i = blockIdx.x * blockDim.x + threadIdx.x; i < total; i += gridDim.x * blockDim.x) {
    int b = i / 800;
    int c4 = (i - b * 800) * 4;
    float4 v;
    if (c4 < 1024)       v = *(const float4*)(x  + (long)b*1024 + c4);
    else if (c4 < 3072)  v = *(const float4*)(th + (long)b*2176 + (c4 - 1024));
    else                 v = *(const float4*)(th + (long)b*2176 + 2048 + (c4 - 3072));
    bf16x4 o = { (bf16_t)v.x, (bf16_t)v.y, (bf16_t)v.z, (bf16_t)v.w };
    *(bf16x4*)(A + (long)i*4) = o;
  }
}

// ---------------- transpose + convert: in fp32 [K][N] (split at K1) -> out bf16 [N][Ktot] ----------------
__global__ __launch_bounds__(256) void transpose_conv_k(const float* __restrict__ in1, int K1,
                                                        const float* __restrict__ in2, int Ktot,
                                                        int N, bf16_t* __restrict__ out) {
  __shared__ float tile[32][33];
  int n0 = blockIdx.x * 32, k0 = blockIdx.y * 32;
  int tx = threadIdx.x, ty = threadIdx.y;  // (32,8)
  #pragma unroll
  for (int r = 0; r < 4; ++r) {
    int k = k0 + ty + r*8;
    float v = (k < K1) ? in1[(long)k*N + n0 + tx] : in2[(long)(k - K1)*N + n0 + tx];
    tile[ty + r*8][tx] = v;
  }
  __syncthreads();
  #pragma unroll
  for (int r = 0; r < 4; ++r) {
    int n = n0 + ty + r*8;
    out[(long)n*Ktot + k0 + tx] = (bf16_t)tile[tx][ty + r*8];
  }
}

// ---------------- bf16 GEMM, split-K via blockIdx.z, 2-phase LDS double-buffer ----------------
template<typename T>
__global__ __launch_bounds__(256) void gemm_bf16_k(const bf16_t* __restrict__ A, int lda,
                                                   const bf16_t* __restrict__ Bt, int ldb,
                                                   T* __restrict__ C, int ldc, int K,
                                                   long coutStride) {
  const int z = blockIdx.z;
  A  += (long)z * K;
  Bt += (long)z * K;
  C  += (long)z * coutStride;
  __shared__ bf16_t sA[2*128*64];
  __shared__ bf16_t sB[2*128*64];
  const int tid = threadIdx.x;
  const int wave = tid >> 6, lane = tid & 63;
  const int tm = blockIdx.y * 128, tn = blockIdx.x * 128;
  const int wm = wave >> 1, wn = wave & 1;
  const int lq = lane >> 4, lr = lane & 15;

  const bf16_t* Ab = A + (long)tm * lda;
  const bf16_t* Bb = Bt + (long)tn * ldb;

  f32x4 acc[4][4];
  #pragma unroll
  for (int m = 0; m < 4; ++m)
    #pragma unroll
    for (int n = 0; n < 4; ++n) { f32x4 zv = {0.f,0.f,0.f,0.f}; acc[m][n] = zv; }

  int rowS[4], kofS[4], ldsoff[4];
  #pragma unroll
  for (int c = 0; c < 4; ++c) {
    int ci = c*256 + tid;
    int row = ci >> 3, kcp = ci & 7;
    int kcl = kcp ^ (row & 7);           // pre-swizzled source chunk
    rowS[c] = row; kofS[c] = kcl * 8;
    ldsoff[c] = (c*256 + wave*64) * 8;   // wave-uniform element offset
  }

#define H_STAGE(BUF, K0)                                                          \
  { const int k0 = (K0);                                                          \
    _Pragma("unroll")                                                             \
    for (int c = 0; c < 4; ++c) {                                                 \
      glds16(Ab + (long)rowS[c]*lda + k0 + kofS[c], sA + (BUF)*8192 + ldsoff[c]); \
      glds16(Bb + (long)rowS[c]*ldb + k0 + kofS[c], sB + (BUF)*8192 + ldsoff[c]); \
    } }

  const int nk = K >> 6;
  int cur = 0;
  H_STAGE(0, 0)
  __syncthreads();
  for (int kt = 0; kt < nk; ++kt) {
    if (kt + 1 < nk) H_STAGE(cur ^ 1, (kt + 1) << 6)
    const bf16_t* aB = sA + cur*8192;
    const bf16_t* bB = sB + cur*8192;
    #pragma unroll
    for (int kk = 0; kk < 64; kk += 32) {
      const int kc = (kk >> 3) + lq;
      bf16x8 af[4], bf[4];
      #pragma unroll
      for (int m = 0; m < 4; ++m) {
        int row = wm*64 + m*16 + lr;
        af[m] = *(const bf16x8*)(aB + row*64 + ((kc ^ (row & 7)) << 3));
      }
      #pragma unroll
      for (int n = 0; n < 4; ++n) {
        int row = wn*64 + n*16 + lr;
        bf[n] = *(const bf16x8*)(bB + row*64 + ((kc ^ (row & 7)) << 3));
      }
      #pragma unroll
      for (int m = 0; m < 4; ++m)
        #pragma unroll
        for (int n = 0; n < 4; ++n)
          acc[m][n] = __builtin_amdgcn_mfma_f32_16x16x32_bf16(af[m], bf[n], acc[m][n], 0, 0, 0);
    }
    __syncthreads();
    cur ^= 1;
  }
#undef H_STAGE

  // epilogue: C/D layout col=lane&15, row=(lane>>4)*4+i
  #pragma unroll
  for (int m = 0; m < 4; ++m)
    #pragma unroll
    for (int i = 0; i < 4; ++i) {
      long row = tm + wm*64 + m*16 + lq*4 + i;
      #pragma unroll
      for (int n = 0; n < 4; ++n) {
        int col = tn + wn*64 + n*16 + lr;
        C[row*ldc + col] = (T)acc[m][n][i];
      }
    }
}

// ---------------- fused dual-acc GEMM + modulation epilogue, 8-wave 128x128 tile ----------------
// Counted-vmcnt pipeline (T4): tiles t,t+1 always in flight; vmcnt(4) waits ONLY the
// oldest 4 loads (tile t); raw s_barrier (no vmcnt(0) drain in the main loop).
// Iter t: vmcnt(4) -> bar -> compute buf[t&1] -> bar -> STAGE(buf[t&1], t+2).
// [Session-best of 6 schedule variants: 361us, VGPR 64, 43% occ. 8-phase 256^2
//  port blocked: dual-acc needs 256 acc regs there; half-tile wait placement
//  underdetermined from docs — do not attempt headless.]
__global__ __launch_bounds__(512, 4) void gemm_fused2_k(const bf16_t* __restrict__ A,
                                                        const bf16_t* __restrict__ Wt,   // [8192][3072]
                                                        const bf16_t* __restrict__ Zbig,
                                                        const bf16_t* __restrict__ Wbig,
                                                        float* __restrict__ gates) {
  __shared__ bf16_t sA[2*128*64];
  __shared__ bf16_t sB[2*128*64];
  const int tid = threadIdx.x;
  const int wave = tid >> 6, lane = tid & 63;
  const int tm = blockIdx.y * 128, tn = blockIdx.x * 128;
  const int wm = wave >> 2, wn = wave & 3;
  const int lq = lane >> 4, lr = lane & 15;

  const bf16_t* Ab = A  + (long)tm * 3200;
  const bf16_t* Bb = Wt + (long)tn * 3072;

  f32x4 accX[4][2], accH[4][2];
  #pragma unroll
  for (int m = 0; m < 4; ++m)
    #pragma unroll
    for (int n = 0; n < 2; ++n) { f32x4 zv = {0.f,0.f,0.f,0.f}; accX[m][n] = zv; accH[m][n] = zv; }

  int rowS[2], kofS[2], ldsoff[2];
  #pragma unroll
  for (int c = 0; c < 2; ++c) {
    int ci = c*512 + tid;
    int row = ci >> 3, kcp = ci & 7;
    int kcl = kcp ^ (row & 7);           // pre-swizzled source chunk
    rowS[c] = row; kofS[c] = kcl * 8;
    ldsoff[c] = (c*512 + wave*64) * 8;   // wave-uniform element offset
  }

#define F_STAGE(BUF, K0)                                                            \
  { const int k0 = (K0);                                                            \
    _Pragma("unroll")                                                               \
    for (int c = 0; c < 2; ++c) {                                                   \
      glds16(Ab + (long)rowS[c]*3200 + k0 + kofS[c], sA + (BUF)*8192 + ldsoff[c]);  \
      glds16(Bb + (long)rowS[c]*3072 + k0 + kofS[c], sB + (BUF)*8192 + ldsoff[c]);  \
    } }

#define F_COMPUTE(BUF, ACC)                                                         \
  { const bf16_t* aB = sA + (BUF)*8192;                                             \
    const bf16_t* bB = sB + (BUF)*8192;                                             \
    _Pragma("unroll")                                                               \
    for (int kk = 0; kk < 64; kk += 32) {                                           \
      const int kc = (kk >> 3) + lq;                                                \
      bf16x8 af[4], bfr[2];                                                         \
      _Pragma("unroll")                                                             \
      for (int m = 0; m < 4; ++m) {                                                 \
        int row = wm*64 + m*16 + lr;                                                \
        af[m] = *(const bf16x8*)(aB + row*64 + ((kc ^ (row & 7)) << 3));            \
      }                                                                             \
      _Pragma("unroll")                                                             \
      for (int n = 0; n < 2; ++n) {                                                 \
        int row = wn*32 + n*16 + lr;                                                \
        bfr[n] = *(const bf16x8*)(bB + row*64 + ((kc ^ (row & 7)) << 3));           \
      }                                                                             \
      _Pragma("unroll")                                                             \
      for (int m = 0; m < 4; ++m)                                                   \
        _Pragma("unroll")                                                           \
        for (int n = 0; n < 2; ++n)                                                 \
          ACC[m][n] = __builtin_amdgcn_mfma_f32_16x16x32_bf16(af[m], bfr[n], ACC[m][n], 0, 0, 0); \
    } }

#define WAITV4 asm volatile("s_waitcnt vmcnt(4)" ::: "memory")
#define WAITV0 asm volatile("s_waitcnt vmcnt(0)" ::: "memory")
#define BAR()  __builtin_amdgcn_s_barrier()

  int cur = 0;
  F_STAGE(0, 0)
  F_STAGE(1, 64)
  // X phase: kt = 0..15 (kt+2 <= 17 < 48, always stage)
  for (int kt = 0; kt < 16; ++kt) {
    WAITV4;                      // tile kt's 4 loads done (oldest of 8)
    BAR();
    F_COMPUTE(cur, accX)
    BAR();
    F_STAGE(cur, (kt + 2) << 6)  // overwrite buf read this iter (safe after barrier)
    cur ^= 1;
  }
  // H phase: kt = 16..47
  for (int kt = 16; kt < 48; ++kt) {
    if (kt < 47) { WAITV4; } else { WAITV0; }
    BAR();
    F_COMPUTE(cur, accH)
    BAR();
    if (kt + 2 < 48) F_STAGE(cur, (kt + 2) << 6)
    cur ^= 1;
  }
#undef F_STAGE
#undef F_COMPUTE
#undef WAITV4
#undef WAITV0
#undef BAR

  // ---- modulation epilogue (Z frags reloaded per-n to cap register liveness) ----
  const int g   = tn >> 11;       // gate index (tile lies within one gate; 256|2048)
  const int cg0 = tn & 2047;      // col offset within gate
  #pragma unroll
  for (int m = 0; m < 4; ++m) {
    const bf16_t* Zr = Zbig + ((long)g*4096 + tm + wm*64 + m*16 + lr) * 256;
    #pragma unroll
    for (int n = 0; n < 2; ++n) {
      const bf16_t* Wc = Wbig + ((long)g*2048 + cg0 + wn*32 + n*16 + lr) * 256;
      f32x4 aX = {0.f,0.f,0.f,0.f};
      f32x4 aH = {0.f,0.f,0.f,0.f};
      f32x4 aC = {0.f,0.f,0.f,0.f};
      {  // X scale: kstep0 (hi*hi + hi*lo + lo*hi)
        bf16x8 zh = *(const bf16x8*)(Zr + 0*32 + lq*8);
        bf16x8 zl = *(const bf16x8*)(Zr + 128 + 0*32 + lq*8);
        bf16x8 wh = *(const bf16x8*)(Wc + 0*32 + lq*8);
        bf16x8 wl = *(const bf16x8*)(Wc + 128 + 0*32 + lq*8);
        aX = __builtin_amdgcn_mfma_f32_16x16x32_bf16(zh, wh, aX, 0,0,0);
        aX = __builtin_amdgcn_mfma_f32_16x16x32_bf16(zh, wl, aX, 0,0,0);
        aX = __builtin_amdgcn_mfma_f32_16x16x32_bf16(zl, wh, aX, 0,0,0);
      }
      {  // H scale: kstep1
        bf16x8 zh = *(const bf16x8*)(Zr + 1*32 + lq*8);
        bf16x8 zl = *(const bf16x8*)(Zr + 128 + 1*32 + lq*8);
        bf16x8 wh = *(const bf16x8*)(Wc + 1*32 + lq*8);
        bf16x8 wl = *(const bf16x8*)(Wc + 128 + 1*32 + lq*8);
        aH = __builtin_amdgcn_mfma_f32_16x16x32_bf16(zh, wh, aH, 0,0,0);
        aH = __builtin_amdgcn_mfma_f32_16x16x32_bf16(zh, wl, aH, 0,0,0);
        aH = __builtin_amdgcn_mfma_f32_16x16x32_bf16(zl, wh, aH, 0,0,0);
      }
      {  // C offset: ksteps 2,3
        bf16x8 zh = *(const bf16x8*)(Zr + 2*32 + lq*8);
        bf16x8 zl = *(const bf16x8*)(Zr + 128 + 2*32 + lq*8);
        bf16x8 wh = *(const bf16x8*)(Wc + 2*32 + lq*8);
        bf16x8 wl = *(const bf16x8*)(Wc + 128 + 2*32 + lq*8);
        aC = __builtin_amdgcn_mfma_f32_16x16x32_bf16(zh, wh, aC, 0,0,0);
        aC = __builtin_amdgcn_mfma_f32_16x16x32_bf16(zh, wl, aC, 0,0,0);
        aC = __builtin_amdgcn_mfma_f32_16x16x32_bf16(zl, wh, aC, 0,0,0);
        zh = *(const bf16x8*)(Zr + 3*32 + lq*8);
        zl = *(const bf16x8*)(Zr + 128 + 3*32 + lq*8);
        wh = *(const bf16x8*)(Wc + 3*32 + lq*8);
        wl = *(const bf16x8*)(Wc + 128 + 3*32 + lq*8);
        aC = __builtin_amdgcn_mfma_f32_16x16x32_bf16(zh, wh, aC, 0,0,0);
        aC = __builtin_amdgcn_mfma_f32_16x16x32_bf16(zh, wl, aC, 0,0,0);
        aC = __builtin_amdgcn_mfma_f32_16x16x32_bf16(zl, wh, aC, 0,0,0);
      }
      #pragma unroll
      for (int i = 0; i < 4; ++i) {
        long row = tm + wm*64 + m*16 + lq*4 + i;
        long col = (long)tn + wn*32 + n*16 + lr;
        gates[row*8192 + col] = aX[i]*accX[m][n][i] + aH[i]*accH[m][n][i] + aC[i];
      }
    }
  }
}

// ---------------- hyper LSTM cell: 1 wave per batch row; sums 5 split-K partials ----------------
__global__ __launch_bounds__(64) void hyper_cell_k(const float* __restrict__ hcat_part,
                                                   const float* __restrict__ tc,
                                                   const float* __restrict__ h_bias,
                                                   const float* __restrict__ hg, const float* __restrict__ hb,
                                                   const float* __restrict__ hcg, const float* __restrict__ hcb,
                                                   float* __restrict__ out, float* __restrict__ hout) {
  const int b = blockIdx.x, l = threadIdx.x;
  const int u0 = 2 * l;
  float v[4][2], nv[4][2];
  #pragma unroll
  for (int g = 0; g < 4; ++g)
    #pragma unroll
    for (int p = 0; p < 2; ++p) {
      long idx = (long)b*512 + g*128 + u0 + p;
      float s = h_bias[g*128 + u0 + p];
      #pragma unroll
      for (int z = 0; z < 5; ++z) s += hcat_part[z*2097152L + idx];
      v[g][p] = s;
    }
  #pragma unroll
  for (int g = 0; g < 4; ++g) {
    float s = v[g][0] + v[g][1];
    float q = v[g][0]*v[g][0] + v[g][1]*v[g][1];
    #pragma unroll
    for (int m = 32; m >= 1; m >>= 1) { s += __shfl_xor(s, m); q += __shfl_xor(q, m); }
    float mean = s * (1.0f/128.0f);
    float inv = rsqrtf(q * (1.0f/128.0f) - mean*mean + EPS);
    #pragma unroll
    for (int p = 0; p < 2; ++p)
      nv[g][p] = (v[g][p] - mean) * inv * hg[g*128 + u0 + p] + hb[g*128 + u0 + p];
  }
  float nc[2], oo[2];
  #pragma unroll
  for (int p = 0; p < 2; ++p) {
    float ii = sigmoidf_(nv[0][p]);
    float jj = tanhf(nv[1][p]);
    float ff = sigmoidf_(nv[2][p] + 1.0f);
    oo[p] = sigmoidf_(nv[3][p]);
    float hc = tc[(long)b*2176 + 2048 + u0 + p];
    nc[p] = hc * ff + ii * jj;
  }
  float s = nc[0] + nc[1], q = nc[0]*nc[0] + nc[1]*nc[1];
  #pragma unroll
  for (int m = 32; m >= 1; m >>= 1) { s += __shfl_xor(s, m); q += __shfl_xor(q, m); }
  float mean = s * (1.0f/128.0f);
  float inv = rsqrtf(q * (1.0f/128.0f) - mean*mean + EPS);
  #pragma unroll
  for (int p = 0; p < 2; ++p) {
    float nh = tanhf((nc[p] - mean) * inv * hcg[u0 + p] + hcb[u0 + p]) * oo[p];
    out[OUT1 + (long)b*2176 + 2048 + u0 + p] = nc[p];
    out[OUT2 + (long)b*2176 + 2048 + u0 + p] = nh;
    hout[(long)b*128 + u0 + p] = nh;
  }
}

// ---------------- zhyper: zw/zb dots -> Zbig[4][4096][2][128] bf16 hi/lo ----------------
// 16 batch rows per block (256 blocks): weights stream once per 16 rows instead of
// once per row (L2 weight traffic 1.6GB -> 100MB). Per-row summation order (u
// ascending) identical to the 1-row version => bit-identical outputs.
__global__ __launch_bounds__(192) void zhyper_k(const float* __restrict__ hout,
                                                const float* __restrict__ zwW, const float* __restrict__ zbias,
                                                const float* __restrict__ zbW,
                                                bf16_t* __restrict__ Zbig) {
  const int r0 = blockIdx.x * 16;
  const int t = threadIdx.x;
  __shared__ float ho[16][128];
  for (int i = t; i < 2048; i += 192) {
    int r = i >> 7, u = i & 127;
    ho[r][u] = hout[(long)(r0 + r)*128 + u];
  }
  // zero-fill pad segs 1,3 for all 4 gates (hi+lo) for these 16 rows
  if (t < 128) {
    int zg = t >> 5, zs = 1 + 2*((t >> 4) & 1), ze = t & 15;
    #pragma unroll
    for (int r = 0; r < 16; ++r) {
      long zbase = ((long)(zg*4096) + r0 + r)*256 + zs*16 + ze;
      Zbig[zbase] = (bf16_t)0.f; Zbig[zbase + 128] = (bf16_t)0.f;
    }
  }
  __syncthreads();
  const int k = t >> 4, e = t & 15;
  const float* wp = zwW + (long)k*2048 + e;
  const float* bp = zbW + (long)k*2048 + e;
  float a[16], a2[16];
  #pragma unroll
  for (int r = 0; r < 16; ++r) { a[r] = 0.f; a2[r] = 0.f; }
  for (int u0 = 0; u0 < 128; u0 += 8) {
    float wv[8], bv[8];
    #pragma unroll
    for (int j = 0; j < 8; ++j) { wv[j] = wp[(u0 + j)*16]; bv[j] = bp[(u0 + j)*16]; }
    #pragma unroll
    for (int r = 0; r < 16; ++r) {
      #pragma unroll
      for (int j = 0; j < 8; ++j) {
        float h = ho[r][u0 + j];
        a[r]  += h * wv[j];
        a2[r] += h * bv[j];
      }
    }
  }
  const float zb0 = zbias[k*16 + e];
  const int g = k & 3, kk = k >> 2;
  const int segA = kk*2;      // 0,2,4
  const int segB = kk + 5;    // 5,6,7
  #pragma unroll
  for (int r = 0; r < 16; ++r) {
    float av = a[r] + zb0;
    long baseg = ((long)(g*4096) + r0 + r)*256;
    bf16_t ah = (bf16_t)av;
    Zbig[baseg + segA*16 + e]       = ah;
    Zbig[baseg + 128 + segA*16 + e] = (bf16_t)(av - (float)ah);
    bf16_t bh = (bf16_t)a2[r];
    Zbig[baseg + segB*16 + e]       = bh;
    Zbig[baseg + 128 + segB*16 + e] = (bf16_t)(a2[r] - (float)bh);
  }
}

// ---------------- wbig: pack weights -> Wbig[4][2048][2][128] bf16 hi/lo (bias folded at seg 4) ----------------
__global__ __launch_bounds__(256) void wbig_k(const float* __restrict__ ww,
                                              const float* __restrict__ bw,
                                              const float* __restrict__ bias,
                                              bf16_t* __restrict__ Wbig) {
  int idx = blockIdx.x * 256 + threadIdx.x;   // 4*2048*16 = 131072 chunks of 8 k
  int c = idx & 15;
  int j = (idx >> 4) & 2047;
  int g = idx >> 15;
  int k0 = c * 8, seg = k0 >> 4, e0 = k0 & 15;
  float v[8];
  for (int u = 0; u < 8; ++u) v[u] = 0.f;
  if (seg == 0) {
    for (int u = 0; u < 8; ++u) v[u] = ww[(long)((g*16) + e0 + u)*2048 + j];
  } else if (seg == 2) {
    for (int u = 0; u < 8; ++u) v[u] = ww[(long)(((4+g)*16) + e0 + u)*2048 + j];
  } else if (seg == 4) {
    float bc = bias[g*2048 + j];
    for (int u = 0; u < 8; ++u) v[u] = ww[(long)(((8+g)*16) + e0 + u)*2048 + j] * bc;
  } else if (seg == 5) {
    for (int u = 0; u < 8; ++u) v[u] = bw[(long)((g*16) + e0 + u)*2048 + j];
  } else if (seg == 6) {
    for (int u = 0; u < 8; ++u) v[u] = bw[(long)(((4+g)*16) + e0 + u)*2048 + j];
  } else if (seg == 7) {
    for (int u = 0; u < 8; ++u) v[u] = bw[(long)(((8+g)*16) + e0 + u)*2048 + j];
  }
  bf16x8 hi, lo;
  for (int u = 0; u < 8; ++u) {
    bf16_t h = (bf16_t)v[u];
    hi[u] = h; lo[u] = (bf16_t)(v[u] - (float)h);
  }
  long base = ((long)(g*2048) + j)*256 + k0;
  *(bf16x8*)(Wbig + base)       = hi;
  *(bf16x8*)(Wbig + base + 128) = lo;
}

// ---------------- M2: main cell — 4 gate-LNs, LSTM update, c-LN, outputs ----------------
__global__ __launch_bounds__(256) void cell_main_k(const float* __restrict__ gates,
                                                   const float* __restrict__ tc,
                                                   const float* __restrict__ lng, const float* __restrict__ lnb,
                                                   const float* __restrict__ lcg, const float* __restrict__ lcb,
                                                   float* __restrict__ out) {
  const int b = blockIdx.x, t = threadIdx.x;
  const int wave = t >> 6, lane = t & 63;
  const int j0 = t * 8;
  float gv[4][8], s[4], q[4];
  #pragma unroll
  for (int g = 0; g < 4; ++g) {
    float4 v0 = *(const float4*)(gates + (long)b*8192 + g*2048 + j0);
    float4 v1 = *(const float4*)(gates + (long)b*8192 + g*2048 + j0 + 4);
    gv[g][0]=v0.x; gv[g][1]=v0.y; gv[g][2]=v0.z; gv[g][3]=v0.w;
    gv[g][4]=v1.x; gv[g][5]=v1.y; gv[g][6]=v1.z; gv[g][7]=v1.w;
    float ls = 0.f, lq = 0.f;
    #pragma unroll
    for (int u = 0; u < 8; ++u) { float f = gv[g][u]; ls += f; lq += f*f; }
    s[g] = ls; q[g] = lq;
  }
  #pragma unroll
  for (int g = 0; g < 4; ++g)
    #pragma unroll
    for (int m = 32; m >= 1; m >>= 1) { s[g] += __shfl_xor(s[g], m); q[g] += __shfl_xor(q[g], m); }
  __shared__ float red[4][4][2];
  if (lane == 0) {
    #pragma unroll
    for (int g = 0; g < 4; ++g) { red[g][wave][0] = s[g]; red[g][wave][1] = q[g]; }
  }
  __syncthreads();
  float mean[4], inv[4];
  #pragma unroll
  for (int g = 0; g < 4; ++g) {
    float S = red[g][0][0] + red[g][1][0] + red[g][2][0] + red[g][3][0];
    float Q = red[g][0][1] + red[g][1][1] + red[g][2][1] + red[g][3][1];
    float m = S * (1.0f/2048.0f);
    mean[g] = m; inv[g] = rsqrtf(Q * (1.0f/2048.0f) - m*m + EPS);
  }
  float nc[8], oo[8];
  const float* cb = tc + (long)b*2176;
  #pragma unroll
  for (int u = 0; u < 8; ++u) {
    int j = j0 + u;
    float iv = (gv[0][u] - mean[0]) * inv[0] * lng[j]        + lnb[j];
    float jv = (gv[1][u] - mean[1]) * inv[1] * lng[2048 + j] + lnb[2048 + j];
    float fv = (gv[2][u] - mean[2]) * inv[2] * lng[4096 + j] + lnb[4096 + j];
    float ov = (gv[3][u] - mean[3]) * inv[3] * lng[6144 + j] + lnb[6144 + j];
    nc[u] = cb[j] * sigmoidf_(fv + 1.0f) + sigmoidf_(iv) * tanhf(jv);
    oo[u] = sigmoidf_(ov);
  }
  float s2 = 0.f, q2 = 0.f;
  #pragma unroll
  for (int u = 0; u < 8; ++u) { s2 += nc[u]; q2 += nc[u]*nc[u]; }
  #pragma unroll
  for (int m = 32; m >= 1; m >>= 1) { s2 += __shfl_xor(s2, m); q2 += __shfl_xor(q2, m); }
  __syncthreads();
  if (lane == 0) { red[0][wave][0] = s2; red[0][wave][1] = q2; }
  __syncthreads();
  float S2 = red[0][0][0] + red[0][1][0] + red[0][2][0] + red[0][3][0];
  float Q2 = red[0][0][1] + red[0][1][1] + red[0][2][1] + red[0][3][1];
  float mc = S2 * (1.0f/2048.0f);
  float ic = rsqrtf(Q2 * (1.0f/2048.0f) - mc*mc + EPS);
  float nh[8];
  #pragma unroll
  for (int u = 0; u < 8; ++u)
    nh[u] = tanhf((nc[u] - mc) * ic * lcg[j0 + u] + lcb[j0 + u]) * oo[u];
  float4 h0 = make_float4(nh[0], nh[1], nh[2], nh[3]);
  float4 h1 = make_float4(nh[4], nh[5], nh[6], nh[7]);
  float4 c0 = make_float4(nc[0], nc[1], nc[2], nc[3]);
  float4 c1 = make_float4(nc[4], nc[5], nc[6], nc[7]);
  *(float4*)(out + (long)b*2048 + j0)            = h0;
  *(float4*)(out + (long)b*2048 + j0 + 4)        = h1;
  *(float4*)(out + OUT1 + (long)b*2176 + j0)     = c0;
  *(float4*)(out + OUT1 + (long)b*2176 + j0 + 4) = c1;
  *(float4*)(out + OUT2 + (long)b*2176 + j0)     = h0;
  *(float4*)(out + OUT2 + (long)b*2176 + j0 + 4) = h1;
}

extern "C" void kernel_launch(void* const* d_in, const int* in_sizes, int n_in,
                              void* d_out, int out_size, void* d_ws, size_t ws_size,
                              hipStream_t stream) {
  const float* x      = (const float*)d_in[0];
  const float* tc     = (const float*)d_in[1];
  const float* th     = (const float*)d_in[2];
  const float* W_xh   = (const float*)d_in[3];
  const float* W_hh   = (const float*)d_in[4];
  const float* bias   = (const float*)d_in[5];
  const float* ln_g   = (const float*)d_in[6];
  const float* ln_b   = (const float*)d_in[7];
  const float* lnc_g  = (const float*)d_in[8];
  const float* lnc_b  = (const float*)d_in[9];
  const float* hW_xh  = (const float*)d_in[10];
  const float* hW_hh  = (const float*)d_in[11];
  const float* h_bias = (const float*)d_in[12];
  const float* h_ln_g = (const float*)d_in[13];
  const float* h_ln_b = (const float*)d_in[14];
  const float* h_lnc_g= (const float*)d_in[15];
  const float* h_lnc_b= (const float*)d_in[16];
  const float* hyp_zw = (const float*)d_in[17];
  const float* hyp_zb = (const float*)d_in[18];
  const float* hyp_ww = (const float*)d_in[19];
  const float* hyp_zbw= (const float*)d_in[20];
  const float* hyp_bw = (const float*)d_in[21];
  float* out = (float*)d_out;

  // Workspace layout. Total ~258 MB.
  char* w = (char*)d_ws;
  bf16_t* A        = (bf16_t*)w;  w += 4096L*3200*2;   //  26,214,400
  bf16_t* WtALL    = (bf16_t*)w;  w += 8192L*3072*2;   //  50,331,648
  bf16_t* WtCAT    = (bf16_t*)w;  w += 512L*3200*2;    //   3,276,800
  float*  hcat_part= (float*)w;   w += 5L*4096*512*4;  //  41,943,040
  float*  hout     = (float*)w;   w += 4096L*128*4;    //   2,097,152
  bf16_t* Zbig     = (bf16_t*)w;  w += 4L*4096*256*2;  //   8,388,608
  bf16_t* Wbig     = (bf16_t*)w;  w += 4L*2048*256*2;  //   4,194,304
  float*  gates    = (float*)w;   w += 4096L*8192*4;   // 134,217,728

  build_A_k<<<2048, 256, 0, stream>>>(x, th, A);
  transpose_conv_k<<<dim3(256, 96),  dim3(32, 8), 0, stream>>>(W_xh, 1024, W_hh, 3072, 8192, WtALL);
  transpose_conv_k<<<dim3(16, 100),  dim3(32, 8), 0, stream>>>(hW_xh, 3072, hW_hh, 3200, 512, WtCAT);
  gemm_bf16_k<float><<<dim3(4, 32, 5), 256, 0, stream>>>(A, 3200, WtCAT, 3200, hcat_part, 512, 640, 4096L*512);
  hyper_cell_k<<<4096, 64, 0, stream>>>(hcat_part, tc, h_bias, h_ln_g, h_ln_b, h_lnc_g, h_lnc_b, out, hout);
  zhyper_k<<<256, 192, 0, stream>>>(hout, hyp_zw, hyp_zb, hyp_zbw, Zbig);
  wbig_k<<<512, 256, 0, stream>>>(hyp_ww, hyp_bw, bias, Wbig);
  gemm_fused2_k<<<dim3(64, 32), 512, 0, stream>>>(A, WtALL, Zbig, Wbig, gates);
  cell_main_k<<<4096, 256, 0, stream>>>(gates, tc, ln_g, ln_b, lnc_g, lnc_b, out);
}

// Round 17
// 637.364 us; speedup vs baseline: 1.3457x; 1.0245x over previous
//
#include <hip/hip_runtime.h>

typedef __bf16 bf16_t;
typedef __attribute__((ext_vector_type(8))) __bf16 bf16x8;
typedef __attribute__((ext_vector_type(4))) __bf16 bf16x4;
typedef __attribute__((ext_vector_type(4))) float f32x4;

#define EPS 1e-3f
#define OUT1 (4096L*2048)
#define OUT2 (OUT1 + 4096L*2176)

__device__ __forceinline__ float sigmoidf_(float x){ return 1.0f/(1.0f+expf(-x)); }

__device__ __forceinline__ void glds16(const void* g, void* l) {
  __builtin_amdgcn_global_load_lds(
      (__attribute__((address_space(1))) void*)g,
      (__attribute__((address_space(3))) void*)l, 16, 0, 0);
}

// ---------------- build A = [x | h | hyper_h] as bf16, [4096][3200] ----------------
__global__ __launch_bounds__(256) void build_A_k(const float* __restrict__ x,
                                                 const float* __restrict__ th,
                                                 bf16_t* __restrict__ A) {
  const int total = 4096 * 800;  // groups of 4 elements
  for (int i = blockIdx.x * blockDim.x + threadIdx.x; i < total; i += gridDim.x * blockDim.x) {
    int b = i / 800;
    int c4 = (i - b * 800) * 4;
    float4 v;
    if (c4 < 1024)       v = *(const float4*)(x  + (long)b*1024 + c4);
    else if (c4 < 3072)  v = *(const float4*)(th + (long)b*2176 + (c4 - 1024));
    else                 v = *(const float4*)(th + (long)b*2176 + 2048 + (c4 - 3072));
    bf16x4 o = { (bf16_t)v.x, (bf16_t)v.y, (bf16_t)v.z, (bf16_t)v.w };
    *(bf16x4*)(A + (long)i*4) = o;
  }
}

// ---------------- transpose + convert: in fp32 [K][N] (split at K1) -> out bf16 [N][Ktot] ----------------
__global__ __launch_bounds__(256) void transpose_conv_k(const float* __restrict__ in1, int K1,
                                                        const float* __restrict__ in2, int Ktot,
                                                        int N, bf16_t* __restrict__ out) {
  __shared__ float tile[32][33];
  int n0 = blockIdx.x * 32, k0 = blockIdx.y * 32;
  int tx = threadIdx.x, ty = threadIdx.y;  // (32,8)
  #pragma unroll
  for (int r = 0; r < 4; ++r) {
    int k = k0 + ty + r*8;
    float v = (k < K1) ? in1[(long)k*N + n0 + tx] : in2[(long)(k - K1)*N + n0 + tx];
    tile[ty + r*8][tx] = v;
  }
  __syncthreads();
  #pragma unroll
  for (int r = 0; r < 4; ++r) {
    int n = n0 + ty + r*8;
    out[(long)n*Ktot + k0 + tx] = (bf16_t)tile[tx][ty + r*8];
  }
}

// ---------------- bf16 GEMM, split-K via blockIdx.z, 2-phase LDS double-buffer ----------------
template<typename T>
__global__ __launch_bounds__(256) void gemm_bf16_k(const bf16_t* __restrict__ A, int lda,
                                                   const bf16_t* __restrict__ Bt, int ldb,
                                                   T* __restrict__ C, int ldc, int K,
                                                   long coutStride) {
  const int z = blockIdx.z;
  A  += (long)z * K;
  Bt += (long)z * K;
  C  += (long)z * coutStride;
  __shared__ bf16_t sA[2*128*64];
  __shared__ bf16_t sB[2*128*64];
  const int tid = threadIdx.x;
  const int wave = tid >> 6, lane = tid & 63;
  const int tm = blockIdx.y * 128, tn = blockIdx.x * 128;
  const int wm = wave >> 1, wn = wave & 1;
  const int lq = lane >> 4, lr = lane & 15;

  const bf16_t* Ab = A + (long)tm * lda;
  const bf16_t* Bb = Bt + (long)tn * ldb;

  f32x4 acc[4][4];
  #pragma unroll
  for (int m = 0; m < 4; ++m)
    #pragma unroll
    for (int n = 0; n < 4; ++n) { f32x4 zv = {0.f,0.f,0.f,0.f}; acc[m][n] = zv; }

  int rowS[4], kofS[4], ldsoff[4];
  #pragma unroll
  for (int c = 0; c < 4; ++c) {
    int ci = c*256 + tid;
    int row = ci >> 3, kcp = ci & 7;
    int kcl = kcp ^ (row & 7);           // pre-swizzled source chunk
    rowS[c] = row; kofS[c] = kcl * 8;
    ldsoff[c] = (c*256 + wave*64) * 8;   // wave-uniform element offset
  }

#define H_STAGE(BUF, K0)                                                          \
  { const int k0 = (K0);                                                          \
    _Pragma("unroll")                                                             \
    for (int c = 0; c < 4; ++c) {                                                 \
      glds16(Ab + (long)rowS[c]*lda + k0 + kofS[c], sA + (BUF)*8192 + ldsoff[c]); \
      glds16(Bb + (long)rowS[c]*ldb + k0 + kofS[c], sB + (BUF)*8192 + ldsoff[c]); \
    } }

  const int nk = K >> 6;
  int cur = 0;
  H_STAGE(0, 0)
  __syncthreads();
  for (int kt = 0; kt < nk; ++kt) {
    if (kt + 1 < nk) H_STAGE(cur ^ 1, (kt + 1) << 6)
    const bf16_t* aB = sA + cur*8192;
    const bf16_t* bB = sB + cur*8192;
    #pragma unroll
    for (int kk = 0; kk < 64; kk += 32) {
      const int kc = (kk >> 3) + lq;
      bf16x8 af[4], bf[4];
      #pragma unroll
      for (int m = 0; m < 4; ++m) {
        int row = wm*64 + m*16 + lr;
        af[m] = *(const bf16x8*)(aB + row*64 + ((kc ^ (row & 7)) << 3));
      }
      #pragma unroll
      for (int n = 0; n < 4; ++n) {
        int row = wn*64 + n*16 + lr;
        bf[n] = *(const bf16x8*)(bB + row*64 + ((kc ^ (row & 7)) << 3));
      }
      #pragma unroll
      for (int m = 0; m < 4; ++m)
        #pragma unroll
        for (int n = 0; n < 4; ++n)
          acc[m][n] = __builtin_amdgcn_mfma_f32_16x16x32_bf16(af[m], bf[n], acc[m][n], 0, 0, 0);
    }
    __syncthreads();
    cur ^= 1;
  }
#undef H_STAGE

  // epilogue: C/D layout col=lane&15, row=(lane>>4)*4+i
  #pragma unroll
  for (int m = 0; m < 4; ++m)
    #pragma unroll
    for (int i = 0; i < 4; ++i) {
      long row = tm + wm*64 + m*16 + lq*4 + i;
      #pragma unroll
      for (int n = 0; n < 4; ++n) {
        int col = tn + wn*64 + n*16 + lr;
        C[row*ldc + col] = (T)acc[m][n][i];
      }
    }
}

// ---------------- fused dual-acc GEMM + modulation epilogue, 8-wave 128x128 tile ----------------
// Counted-vmcnt pipeline (T4): tiles t,t+1 always in flight; vmcnt(4) waits ONLY the
// oldest 4 loads (tile t); raw s_barrier (no vmcnt(0) drain in the main loop).
// Iter t: vmcnt(4) -> bar -> compute buf[t&1] -> bar -> STAGE(buf[t&1], t+2).
// [Session-best of 6 schedule variants: 361us, VGPR 64, 43% occ.]
// gates stored as bf16 (halves gates traffic; absmax model: ~0.0220 < 0.0244 thr,
// anchored by R1 (3 bf16 stores = 0.02515) / R2 (fp32 = 0.02026) measurements).
__global__ __launch_bounds__(512, 4) void gemm_fused2_k(const bf16_t* __restrict__ A,
                                                        const bf16_t* __restrict__ Wt,   // [8192][3072]
                                                        const bf16_t* __restrict__ Zbig,
                                                        const bf16_t* __restrict__ Wbig,
                                                        bf16_t* __restrict__ gates) {
  __shared__ bf16_t sA[2*128*64];
  __shared__ bf16_t sB[2*128*64];
  const int tid = threadIdx.x;
  const int wave = tid >> 6, lane = tid & 63;
  const int tm = blockIdx.y * 128, tn = blockIdx.x * 128;
  const int wm = wave >> 2, wn = wave & 3;
  const int lq = lane >> 4, lr = lane & 15;

  const bf16_t* Ab = A  + (long)tm * 3200;
  const bf16_t* Bb = Wt + (long)tn * 3072;

  f32x4 accX[4][2], accH[4][2];
  #pragma unroll
  for (int m = 0; m < 4; ++m)
    #pragma unroll
    for (int n = 0; n < 2; ++n) { f32x4 zv = {0.f,0.f,0.f,0.f}; accX[m][n] = zv; accH[m][n] = zv; }

  int rowS[2], kofS[2], ldsoff[2];
  #pragma unroll
  for (int c = 0; c < 2; ++c) {
    int ci = c*512 + tid;
    int row = ci >> 3, kcp = ci & 7;
    int kcl = kcp ^ (row & 7);           // pre-swizzled source chunk
    rowS[c] = row; kofS[c] = kcl * 8;
    ldsoff[c] = (c*512 + wave*64) * 8;   // wave-uniform element offset
  }

#define F_STAGE(BUF, K0)                                                            \
  { const int k0 = (K0);                                                            \
    _Pragma("unroll")                                                               \
    for (int c = 0; c < 2; ++c) {                                                   \
      glds16(Ab + (long)rowS[c]*3200 + k0 + kofS[c], sA + (BUF)*8192 + ldsoff[c]);  \
      glds16(Bb + (long)rowS[c]*3072 + k0 + kofS[c], sB + (BUF)*8192 + ldsoff[c]);  \
    } }

#define F_COMPUTE(BUF, ACC)                                                         \
  { const bf16_t* aB = sA + (BUF)*8192;                                             \
    const bf16_t* bB = sB + (BUF)*8192;                                             \
    _Pragma("unroll")                                                               \
    for (int kk = 0; kk < 64; kk += 32) {                                           \
      const int kc = (kk >> 3) + lq;                                                \
      bf16x8 af[4], bfr[2];                                                         \
      _Pragma("unroll")                                                             \
      for (int m = 0; m < 4; ++m) {                                                 \
        int row = wm*64 + m*16 + lr;                                                \
        af[m] = *(const bf16x8*)(aB + row*64 + ((kc ^ (row & 7)) << 3));            \
      }                                                                             \
      _Pragma("unroll")                                                             \
      for (int n = 0; n < 2; ++n) {                                                 \
        int row = wn*32 + n*16 + lr;                                                \
        bfr[n] = *(const bf16x8*)(bB + row*64 + ((kc ^ (row & 7)) << 3));           \
      }                                                                             \
      _Pragma("unroll")                                                             \
      for (int m = 0; m < 4; ++m)                                                   \
        _Pragma("unroll")                                                           \
        for (int n = 0; n < 2; ++n)                                                 \
          ACC[m][n] = __builtin_amdgcn_mfma_f32_16x16x32_bf16(af[m], bfr[n], ACC[m][n], 0, 0, 0); \
    } }

#define WAITV4 asm volatile("s_waitcnt vmcnt(4)" ::: "memory")
#define WAITV0 asm volatile("s_waitcnt vmcnt(0)" ::: "memory")
#define BAR()  __builtin_amdgcn_s_barrier()

  int cur = 0;
  F_STAGE(0, 0)
  F_STAGE(1, 64)
  // X phase: kt = 0..15 (kt+2 <= 17 < 48, always stage)
  for (int kt = 0; kt < 16; ++kt) {
    WAITV4;                      // tile kt's 4 loads done (oldest of 8)
    BAR();
    F_COMPUTE(cur, accX)
    BAR();
    F_STAGE(cur, (kt + 2) << 6)  // overwrite buf read this iter (safe after barrier)
    cur ^= 1;
  }
  // H phase: kt = 16..47
  for (int kt = 16; kt < 48; ++kt) {
    if (kt < 47) { WAITV4; } else { WAITV0; }
    BAR();
    F_COMPUTE(cur, accH)
    BAR();
    if (kt + 2 < 48) F_STAGE(cur, (kt + 2) << 6)
    cur ^= 1;
  }
#undef F_STAGE
#undef F_COMPUTE
#undef WAITV4
#undef WAITV0
#undef BAR

  // ---- modulation epilogue (Z frags reloaded per-n to cap register liveness) ----
  const int g   = tn >> 11;       // gate index (tile lies within one gate; 256|2048)
  const int cg0 = tn & 2047;      // col offset within gate
  #pragma unroll
  for (int m = 0; m < 4; ++m) {
    const bf16_t* Zr = Zbig + ((long)g*4096 + tm + wm*64 + m*16 + lr) * 256;
    #pragma unroll
    for (int n = 0; n < 2; ++n) {
      const bf16_t* Wc = Wbig + ((long)g*2048 + cg0 + wn*32 + n*16 + lr) * 256;
      f32x4 aX = {0.f,0.f,0.f,0.f};
      f32x4 aH = {0.f,0.f,0.f,0.f};
      f32x4 aC = {0.f,0.f,0.f,0.f};
      {  // X scale: kstep0 (hi*hi + hi*lo + lo*hi)
        bf16x8 zh = *(const bf16x8*)(Zr + 0*32 + lq*8);
        bf16x8 zl = *(const bf16x8*)(Zr + 128 + 0*32 + lq*8);
        bf16x8 wh = *(const bf16x8*)(Wc + 0*32 + lq*8);
        bf16x8 wl = *(const bf16x8*)(Wc + 128 + 0*32 + lq*8);
        aX = __builtin_amdgcn_mfma_f32_16x16x32_bf16(zh, wh, aX, 0,0,0);
        aX = __builtin_amdgcn_mfma_f32_16x16x32_bf16(zh, wl, aX, 0,0,0);
        aX = __builtin_amdgcn_mfma_f32_16x16x32_bf16(zl, wh, aX, 0,0,0);
      }
      {  // H scale: kstep1
        bf16x8 zh = *(const bf16x8*)(Zr + 1*32 + lq*8);
        bf16x8 zl = *(const bf16x8*)(Zr + 128 + 1*32 + lq*8);
        bf16x8 wh = *(const bf16x8*)(Wc + 1*32 + lq*8);
        bf16x8 wl = *(const bf16x8*)(Wc + 128 + 1*32 + lq*8);
        aH = __builtin_amdgcn_mfma_f32_16x16x32_bf16(zh, wh, aH, 0,0,0);
        aH = __builtin_amdgcn_mfma_f32_16x16x32_bf16(zh, wl, aH, 0,0,0);
        aH = __builtin_amdgcn_mfma_f32_16x16x32_bf16(zl, wh, aH, 0,0,0);
      }
      {  // C offset: ksteps 2,3
        bf16x8 zh = *(const bf16x8*)(Zr + 2*32 + lq*8);
        bf16x8 zl = *(const bf16x8*)(Zr + 128 + 2*32 + lq*8);
        bf16x8 wh = *(const bf16x8*)(Wc + 2*32 + lq*8);
        bf16x8 wl = *(const bf16x8*)(Wc + 128 + 2*32 + lq*8);
        aC = __builtin_amdgcn_mfma_f32_16x16x32_bf16(zh, wh, aC, 0,0,0);
        aC = __builtin_amdgcn_mfma_f32_16x16x32_bf16(zh, wl, aC, 0,0,0);
        aC = __builtin_amdgcn_mfma_f32_16x16x32_bf16(zl, wh, aC, 0,0,0);
        zh = *(const bf16x8*)(Zr + 3*32 + lq*8);
        zl = *(const bf16x8*)(Zr + 128 + 3*32 + lq*8);
        wh = *(const bf16x8*)(Wc + 3*32 + lq*8);
        wl = *(const bf16x8*)(Wc + 128 + 3*32 + lq*8);
        aC = __builtin_amdgcn_mfma_f32_16x16x32_bf16(zh, wh, aC, 0,0,0);
        aC = __builtin_amdgcn_mfma_f32_16x16x32_bf16(zh, wl, aC, 0,0,0);
        aC = __builtin_amdgcn_mfma_f32_16x16x32_bf16(zl, wh, aC, 0,0,0);
      }
      #pragma unroll
      for (int i = 0; i < 4; ++i) {
        long row = tm + wm*64 + m*16 + lq*4 + i;
        long col = (long)tn + wn*32 + n*16 + lr;
        gates[row*8192 + col] = (bf16_t)(aX[i]*accX[m][n][i] + aH[i]*accH[m][n][i] + aC[i]);
      }
    }
  }
}

// ---------------- hyper LSTM cell: 1 wave per batch row; sums 5 split-K partials ----------------
__global__ __launch_bounds__(64) void hyper_cell_k(const float* __restrict__ hcat_part,
                                                   const float* __restrict__ tc,
                                                   const float* __restrict__ h_bias,
                                                   const float* __restrict__ hg, const float* __restrict__ hb,
                                                   const float* __restrict__ hcg, const float* __restrict__ hcb,
                                                   float* __restrict__ out, float* __restrict__ hout) {
  const int b = blockIdx.x, l = threadIdx.x;
  const int u0 = 2 * l;
  float v[4][2], nv[4][2];
  #pragma unroll
  for (int g = 0; g < 4; ++g)
    #pragma unroll
    for (int p = 0; p < 2; ++p) {
      long idx = (long)b*512 + g*128 + u0 + p;
      float s = h_bias[g*128 + u0 + p];
      #pragma unroll
      for (int z = 0; z < 5; ++z) s += hcat_part[z*2097152L + idx];
      v[g][p] = s;
    }
  #pragma unroll
  for (int g = 0; g < 4; ++g) {
    float s = v[g][0] + v[g][1];
    float q = v[g][0]*v[g][0] + v[g][1]*v[g][1];
    #pragma unroll
    for (int m = 32; m >= 1; m >>= 1) { s += __shfl_xor(s, m); q += __shfl_xor(q, m); }
    float mean = s * (1.0f/128.0f);
    float inv = rsqrtf(q * (1.0f/128.0f) - mean*mean + EPS);
    #pragma unroll
    for (int p = 0; p < 2; ++p)
      nv[g][p] = (v[g][p] - mean) * inv * hg[g*128 + u0 + p] + hb[g*128 + u0 + p];
  }
  float nc[2], oo[2];
  #pragma unroll
  for (int p = 0; p < 2; ++p) {
    float ii = sigmoidf_(nv[0][p]);
    float jj = tanhf(nv[1][p]);
    float ff = sigmoidf_(nv[2][p] + 1.0f);
    oo[p] = sigmoidf_(nv[3][p]);
    float hc = tc[(long)b*2176 + 2048 + u0 + p];
    nc[p] = hc * ff + ii * jj;
  }
  float s = nc[0] + nc[1], q = nc[0]*nc[0] + nc[1]*nc[1];
  #pragma unroll
  for (int m = 32; m >= 1; m >>= 1) { s += __shfl_xor(s, m); q += __shfl_xor(q, m); }
  float mean = s * (1.0f/128.0f);
  float inv = rsqrtf(q * (1.0f/128.0f) - mean*mean + EPS);
  #pragma unroll
  for (int p = 0; p < 2; ++p) {
    float nh = tanhf((nc[p] - mean) * inv * hcg[u0 + p] + hcb[u0 + p]) * oo[p];
    out[OUT1 + (long)b*2176 + 2048 + u0 + p] = nc[p];
    out[OUT2 + (long)b*2176 + 2048 + u0 + p] = nh;
    hout[(long)b*128 + u0 + p] = nh;
  }
}

// ---------------- zhyper: zw/zb dots -> Zbig[4][4096][2][128] bf16 hi/lo ----------------
// 16 batch rows per block (256 blocks): weights stream once per 16 rows.
__global__ __launch_bounds__(192) void zhyper_k(const float* __restrict__ hout,
                                                const float* __restrict__ zwW, const float* __restrict__ zbias,
                                                const float* __restrict__ zbW,
                                                bf16_t* __restrict__ Zbig) {
  const int r0 = blockIdx.x * 16;
  const int t = threadIdx.x;
  __shared__ float ho[16][128];
  for (int i = t; i < 2048; i += 192) {
    int r = i >> 7, u = i & 127;
    ho[r][u] = hout[(long)(r0 + r)*128 + u];
  }
  // zero-fill pad segs 1,3 for all 4 gates (hi+lo) for these 16 rows
  if (t < 128) {
    int zg = t >> 5, zs = 1 + 2*((t >> 4) & 1), ze = t & 15;
    #pragma unroll
    for (int r = 0; r < 16; ++r) {
      long zbase = ((long)(zg*4096) + r0 + r)*256 + zs*16 + ze;
      Zbig[zbase] = (bf16_t)0.f; Zbig[zbase + 128] = (bf16_t)0.f;
    }
  }
  __syncthreads();
  const int k = t >> 4, e = t & 15;
  const float* wp = zwW + (long)k*2048 + e;
  const float* bp = zbW + (long)k*2048 + e;
  float a[16], a2[16];
  #pragma unroll
  for (int r = 0; r < 16; ++r) { a[r] = 0.f; a2[r] = 0.f; }
  for (int u0 = 0; u0 < 128; u0 += 8) {
    float wv[8], bv[8];
    #pragma unroll
    for (int j = 0; j < 8; ++j) { wv[j] = wp[(u0 + j)*16]; bv[j] = bp[(u0 + j)*16]; }
    #pragma unroll
    for (int r = 0; r < 16; ++r) {
      #pragma unroll
      for (int j = 0; j < 8; ++j) {
        float h = ho[r][u0 + j];
        a[r]  += h * wv[j];
        a2[r] += h * bv[j];
      }
    }
  }
  const float zb0 = zbias[k*16 + e];
  const int g = k & 3, kk = k >> 2;
  const int segA = kk*2;      // 0,2,4
  const int segB = kk + 5;    // 5,6,7
  #pragma unroll
  for (int r = 0; r < 16; ++r) {
    float av = a[r] + zb0;
    long baseg = ((long)(g*4096) + r0 + r)*256;
    bf16_t ah = (bf16_t)av;
    Zbig[baseg + segA*16 + e]       = ah;
    Zbig[baseg + 128 + segA*16 + e] = (bf16_t)(av - (float)ah);
    bf16_t bh = (bf16_t)a2[r];
    Zbig[baseg + segB*16 + e]       = bh;
    Zbig[baseg + 128 + segB*16 + e] = (bf16_t)(a2[r] - (float)bh);
  }
}

// ---------------- wbig: pack weights -> Wbig[4][2048][2][128] bf16 hi/lo (bias folded at seg 4) ----------------
__global__ __launch_bounds__(256) void wbig_k(const float* __restrict__ ww,
                                              const float* __restrict__ bw,
                                              const float* __restrict__ bias,
                                              bf16_t* __restrict__ Wbig) {
  int idx = blockIdx.x * 256 + threadIdx.x;   // 4*2048*16 = 131072 chunks of 8 k
  int c = idx & 15;
  int j = (idx >> 4) & 2047;
  int g = idx >> 15;
  int k0 = c * 8, seg = k0 >> 4, e0 = k0 & 15;
  float v[8];
  for (int u = 0; u < 8; ++u) v[u] = 0.f;
  if (seg == 0) {
    for (int u = 0; u < 8; ++u) v[u] = ww[(long)((g*16) + e0 + u)*2048 + j];
  } else if (seg == 2) {
    for (int u = 0; u < 8; ++u) v[u] = ww[(long)(((4+g)*16) + e0 + u)*2048 + j];
  } else if (seg == 4) {
    float bc = bias[g*2048 + j];
    for (int u = 0; u < 8; ++u) v[u] = ww[(long)(((8+g)*16) + e0 + u)*2048 + j] * bc;
  } else if (seg == 5) {
    for (int u = 0; u < 8; ++u) v[u] = bw[(long)((g*16) + e0 + u)*2048 + j];
  } else if (seg == 6) {
    for (int u = 0; u < 8; ++u) v[u] = bw[(long)(((4+g)*16) + e0 + u)*2048 + j];
  } else if (seg == 7) {
    for (int u = 0; u < 8; ++u) v[u] = bw[(long)(((8+g)*16) + e0 + u)*2048 + j];
  }
  bf16x8 hi, lo;
  for (int u = 0; u < 8; ++u) {
    bf16_t h = (bf16_t)v[u];
    hi[u] = h; lo[u] = (bf16_t)(v[u] - (float)h);
  }
  long base = ((long)(g*2048) + j)*256 + k0;
  *(bf16x8*)(Wbig + base)       = hi;
  *(bf16x8*)(Wbig + base + 128) = lo;
}

// ---------------- M2: main cell — 4 gate-LNs, LSTM update, c-LN, outputs (bf16 gates in) ----------------
__global__ __launch_bounds__(256) void cell_main_k(const bf16_t* __restrict__ gates,
                                                   const float* __restrict__ tc,
                                                   const float* __restrict__ lng, const float* __restrict__ lnb,
                                                   const float* __restrict__ lcg, const float* __restrict__ lcb,
                                                   float* __restrict__ out) {
  const int b = blockIdx.x, t = threadIdx.x;
  const int wave = t >> 6, lane = t & 63;
  const int j0 = t * 8;
  float gv[4][8], s[4], q[4];
  #pragma unroll
  for (int g = 0; g < 4; ++g) {
    bf16x8 v = *(const bf16x8*)(gates + (long)b*8192 + g*2048 + j0);
    float ls = 0.f, lq = 0.f;
    #pragma unroll
    for (int u = 0; u < 8; ++u) { float f = (float)v[u]; gv[g][u] = f; ls += f; lq += f*f; }
    s[g] = ls; q[g] = lq;
  }
  #pragma unroll
  for (int g = 0; g < 4; ++g)
    #pragma unroll
    for (int m = 32; m >= 1; m >>= 1) { s[g] += __shfl_xor(s[g], m); q[g] += __shfl_xor(q[g], m); }
  __shared__ float red[4][4][2];
  if (lane == 0) {
    #pragma unroll
    for (int g = 0; g < 4; ++g) { red[g][wave][0] = s[g]; red[g][wave][1] = q[g]; }
  }
  __syncthreads();
  float mean[4], inv[4];
  #pragma unroll
  for (int g = 0; g < 4; ++g) {
    float S = red[g][0][0] + red[g][1][0] + red[g][2][0] + red[g][3][0];
    float Q = red[g][0][1] + red[g][1][1] + red[g][2][1] + red[g][3][1];
    float m = S * (1.0f/2048.0f);
    mean[g] = m; inv[g] = rsqrtf(Q * (1.0f/2048.0f) - m*m + EPS);
  }
  float nc[8], oo[8];
  const float* cb = tc + (long)b*2176;
  #pragma unroll
  for (int u = 0; u < 8; ++u) {
    int j = j0 + u;
    float iv = (gv[0][u] - mean[0]) * inv[0] * lng[j]        + lnb[j];
    float jv = (gv[1][u] - mean[1]) * inv[1] * lng[2048 + j] + lnb[2048 + j];
    float fv = (gv[2][u] - mean[2]) * inv[2] * lng[4096 + j] + lnb[4096 + j];
    float ov = (gv[3][u] - mean[3]) * inv[3] * lng[6144 + j] + lnb[6144 + j];
    nc[u] = cb[j] * sigmoidf_(fv + 1.0f) + sigmoidf_(iv) * tanhf(jv);
    oo[u] = sigmoidf_(ov);
  }
  float s2 = 0.f, q2 = 0.f;
  #pragma unroll
  for (int u = 0; u < 8; ++u) { s2 += nc[u]; q2 += nc[u]*nc[u]; }
  #pragma unroll
  for (int m = 32; m >= 1; m >>= 1) { s2 += __shfl_xor(s2, m); q2 += __shfl_xor(q2, m); }
  __syncthreads();
  if (lane == 0) { red[0][wave][0] = s2; red[0][wave][1] = q2; }
  __syncthreads();
  float S2 = red[0][0][0] + red[0][1][0] + red[0][2][0] + red[0][3][0];
  float Q2 = red[0][0][1] + red[0][1][1] + red[0][2][1] + red[0][3][1];
  float mc = S2 * (1.0f/2048.0f);
  float ic = rsqrtf(Q2 * (1.0f/2048.0f) - mc*mc + EPS);
  float nh[8];
  #pragma unroll
  for (int u = 0; u < 8; ++u)
    nh[u] = tanhf((nc[u] - mc) * ic * lcg[j0 + u] + lcb[j0 + u]) * oo[u];
  float4 h0 = make_float4(nh[0], nh[1], nh[2], nh[3]);
  float4 h1 = make_float4(nh[4], nh[5], nh[6], nh[7]);
  float4 c0 = make_float4(nc[0], nc[1], nc[2], nc[3]);
  float4 c1 = make_float4(nc[4], nc[5], nc[6], nc[7]);
  *(float4*)(out + (long)b*2048 + j0)            = h0;
  *(float4*)(out + (long)b*2048 + j0 + 4)        = h1;
  *(float4*)(out + OUT1 + (long)b*2176 + j0)     = c0;
  *(float4*)(out + OUT1 + (long)b*2176 + j0 + 4) = c1;
  *(float4*)(out + OUT2 + (long)b*2176 + j0)     = h0;
  *(float4*)(out + OUT2 + (long)b*2176 + j0 + 4) = h1;
}

extern "C" void kernel_launch(void* const* d_in, const int* in_sizes, int n_in,
                              void* d_out, int out_size, void* d_ws, size_t ws_size,
                              hipStream_t stream) {
  const float* x      = (const float*)d_in[0];
  const float* tc     = (const float*)d_in[1];
  const float* th     = (const float*)d_in[2];
  const float* W_xh   = (const float*)d_in[3];
  const float* W_hh   = (const float*)d_in[4];
  const float* bias   = (const float*)d_in[5];
  const float* ln_g   = (const float*)d_in[6];
  const float* ln_b   = (const float*)d_in[7];
  const float* lnc_g  = (const float*)d_in[8];
  const float* lnc_b  = (const float*)d_in[9];
  const float* hW_xh  = (const float*)d_in[10];
  const float* hW_hh  = (const float*)d_in[11];
  const float* h_bias = (const float*)d_in[12];
  const float* h_ln_g = (const float*)d_in[13];
  const float* h_ln_b = (const float*)d_in[14];
  const float* h_lnc_g= (const float*)d_in[15];
  const float* h_lnc_b= (const float*)d_in[16];
  const float* hyp_zw = (const float*)d_in[17];
  const float* hyp_zb = (const float*)d_in[18];
  const float* hyp_ww = (const float*)d_in[19];
  const float* hyp_zbw= (const float*)d_in[20];
  const float* hyp_bw = (const float*)d_in[21];
  float* out = (float*)d_out;

  // Workspace layout. Total ~191 MB (gates now bf16).
  char* w = (char*)d_ws;
  bf16_t* A        = (bf16_t*)w;  w += 4096L*3200*2;   //  26,214,400
  bf16_t* WtALL    = (bf16_t*)w;  w += 8192L*3072*2;   //  50,331,648
  bf16_t* WtCAT    = (bf16_t*)w;  w += 512L*3200*2;    //   3,276,800
  float*  hcat_part= (float*)w;   w += 5L*4096*512*4;  //  41,943,040
  float*  hout     = (float*)w;   w += 4096L*128*4;    //   2,097,152
  bf16_t* Zbig     = (bf16_t*)w;  w += 4L*4096*256*2;  //   8,388,608
  bf16_t* Wbig     = (bf16_t*)w;  w += 4L*2048*256*2;  //   4,194,304
  bf16_t* gates    = (bf16_t*)w;  w += 4096L*8192*2;   //  67,108,864

  build_A_k<<<2048, 256, 0, stream>>>(x, th, A);
  transpose_conv_k<<<dim3(256, 96),  dim3(32, 8), 0, stream>>>(W_xh, 1024, W_hh, 3072, 8192, WtALL);
  transpose_conv_k<<<dim3(16, 100),  dim3(32, 8), 0, stream>>>(hW_xh, 3072, hW_hh, 3200, 512, WtCAT);
  gemm_bf16_k<float><<<dim3(4, 32, 5), 256, 0, stream>>>(A, 3200, WtCAT, 3200, hcat_part, 512, 640, 4096L*512);
  hyper_cell_k<<<4096, 64, 0, stream>>>(hcat_part, tc, h_bias, h_ln_g, h_ln_b, h_lnc_g, h_lnc_b, out, hout);
  zhyper_k<<<256, 192, 0, stream>>>(hout, hyp_zw, hyp_zb, hyp_zbw, Zbig);
  wbig_k<<<512, 256, 0, stream>>>(hyp_ww, hyp_bw, bias, Wbig);
  gemm_fused2_k<<<dim3(64, 32), 512, 0, stream>>>(A, WtALL, Zbig, Wbig, gates);
  cell_main_k<<<4096, 256, 0, stream>>>(gates, tc, ln_g, ln_b, lnc_g, lnc_b, out);
}

// Round 18
// 520.337 us; speedup vs baseline: 1.6483x; 1.2249x over previous
//
#include <hip/hip_runtime.h>

typedef __bf16 bf16_t;
typedef __attribute__((ext_vector_type(8))) __bf16 bf16x8;
typedef __attribute__((ext_vector_type(4))) __bf16 bf16x4;
typedef __attribute__((ext_vector_type(4))) float f32x4;

#define EPS 1e-3f
#define OUT1 (4096L*2048)
#define OUT2 (OUT1 + 4096L*2176)

// Fast transcendentals via HW v_exp_f32 (rel err ~1e-6 << bf16 tolerance).
__device__ __forceinline__ float sigmoidf_(float x){ return 1.0f/(1.0f+__expf(-x)); }
__device__ __forceinline__ float tanhf_(float x){
  float e = __expf(-2.0f*fabsf(x));          // e in (0,1]; no overflow
  float r = (1.0f - e)/(1.0f + e);
  return copysignf(r, x);
}

__device__ __forceinline__ void glds16(const void* g, void* l) {
  __builtin_amdgcn_global_load_lds(
      (__attribute__((address_space(1))) void*)g,
      (__attribute__((address_space(3))) void*)l, 16, 0, 0);
}

// ---------------- build A = [x | h | hyper_h] as bf16, [4096][3200] ----------------
__global__ __launch_bounds__(256) void build_A_k(const float* __restrict__ x,
                                                 const float* __restrict__ th,
                                                 bf16_t* __restrict__ A) {
  const int total = 4096 * 800;  // groups of 4 elements
  for (int i = blockIdx.x * blockDim.x + threadIdx.x; i < total; i += gridDim.x * blockDim.x) {
    int b = i / 800;
    int c4 = (i - b * 800) * 4;
    float4 v;
    if (c4 < 1024)       v = *(const float4*)(x  + (long)b*1024 + c4);
    else if (c4 < 3072)  v = *(const float4*)(th + (long)b*2176 + (c4 - 1024));
    else                 v = *(const float4*)(th + (long)b*2176 + 2048 + (c4 - 3072));
    bf16x4 o = { (bf16_t)v.x, (bf16_t)v.y, (bf16_t)v.z, (bf16_t)v.w };
    *(bf16x4*)(A + (long)i*4) = o;
  }
}

// ---------------- transpose + convert: in fp32 [K][N] (split at K1) -> out bf16 [N][Ktot] ----------------
__global__ __launch_bounds__(256) void transpose_conv_k(const float* __restrict__ in1, int K1,
                                                        const float* __restrict__ in2, int Ktot,
                                                        int N, bf16_t* __restrict__ out) {
  __shared__ float tile[32][33];
  int n0 = blockIdx.x * 32, k0 = blockIdx.y * 32;
  int tx = threadIdx.x, ty = threadIdx.y;  // (32,8)
  #pragma unroll
  for (int r = 0; r < 4; ++r) {
    int k = k0 + ty + r*8;
    float v = (k < K1) ? in1[(long)k*N + n0 + tx] : in2[(long)(k - K1)*N + n0 + tx];
    tile[ty + r*8][tx] = v;
  }
  __syncthreads();
  #pragma unroll
  for (int r = 0; r < 4; ++r) {
    int n = n0 + ty + r*8;
    out[(long)n*Ktot + k0 + tx] = (bf16_t)tile[tx][ty + r*8];
  }
}

// ---------------- bf16 GEMM, split-K via blockIdx.z, 2-phase LDS double-buffer ----------------
template<typename T>
__global__ __launch_bounds__(256) void gemm_bf16_k(const bf16_t* __restrict__ A, int lda,
                                                   const bf16_t* __restrict__ Bt, int ldb,
                                                   T* __restrict__ C, int ldc, int K,
                                                   long coutStride) {
  const int z = blockIdx.z;
  A  += (long)z * K;
  Bt += (long)z * K;
  C  += (long)z * coutStride;
  __shared__ bf16_t sA[2*128*64];
  __shared__ bf16_t sB[2*128*64];
  const int tid = threadIdx.x;
  const int wave = tid >> 6, lane = tid & 63;
  const int tm = blockIdx.y * 128, tn = blockIdx.x * 128;
  const int wm = wave >> 1, wn = wave & 1;
  const int lq = lane >> 4, lr = lane & 15;

  const bf16_t* Ab = A + (long)tm * lda;
  const bf16_t* Bb = Bt + (long)tn * ldb;

  f32x4 acc[4][4];
  #pragma unroll
  for (int m = 0; m < 4; ++m)
    #pragma unroll
    for (int n = 0; n < 4; ++n) { f32x4 zv = {0.f,0.f,0.f,0.f}; acc[m][n] = zv; }

  int rowS[4], kofS[4], ldsoff[4];
  #pragma unroll
  for (int c = 0; c < 4; ++c) {
    int ci = c*256 + tid;
    int row = ci >> 3, kcp = ci & 7;
    int kcl = kcp ^ (row & 7);           // pre-swizzled source chunk
    rowS[c] = row; kofS[c] = kcl * 8;
    ldsoff[c] = (c*256 + wave*64) * 8;   // wave-uniform element offset
  }

#define H_STAGE(BUF, K0)                                                          \
  { const int k0 = (K0);                                                          \
    _Pragma("unroll")                                                             \
    for (int c = 0; c < 4; ++c) {                                                 \
      glds16(Ab + (long)rowS[c]*lda + k0 + kofS[c], sA + (BUF)*8192 + ldsoff[c]); \
      glds16(Bb + (long)rowS[c]*ldb + k0 + kofS[c], sB + (BUF)*8192 + ldsoff[c]); \
    } }

  const int nk = K >> 6;
  int cur = 0;
  H_STAGE(0, 0)
  __syncthreads();
  for (int kt = 0; kt < nk; ++kt) {
    if (kt + 1 < nk) H_STAGE(cur ^ 1, (kt + 1) << 6)
    const bf16_t* aB = sA + cur*8192;
    const bf16_t* bB = sB + cur*8192;
    #pragma unroll
    for (int kk = 0; kk < 64; kk += 32) {
      const int kc = (kk >> 3) + lq;
      bf16x8 af[4], bf[4];
      #pragma unroll
      for (int m = 0; m < 4; ++m) {
        int row = wm*64 + m*16 + lr;
        af[m] = *(const bf16x8*)(aB + row*64 + ((kc ^ (row & 7)) << 3));
      }
      #pragma unroll
      for (int n = 0; n < 4; ++n) {
        int row = wn*64 + n*16 + lr;
        bf[n] = *(const bf16x8*)(bB + row*64 + ((kc ^ (row & 7)) << 3));
      }
      #pragma unroll
      for (int m = 0; m < 4; ++m)
        #pragma unroll
        for (int n = 0; n < 4; ++n)
          acc[m][n] = __builtin_amdgcn_mfma_f32_16x16x32_bf16(af[m], bf[n], acc[m][n], 0, 0, 0);
    }
    __syncthreads();
    cur ^= 1;
  }
#undef H_STAGE

  // epilogue: C/D layout col=lane&15, row=(lane>>4)*4+i
  #pragma unroll
  for (int m = 0; m < 4; ++m)
    #pragma unroll
    for (int i = 0; i < 4; ++i) {
      long row = tm + wm*64 + m*16 + lq*4 + i;
      #pragma unroll
      for (int n = 0; n < 4; ++n) {
        int col = tn + wn*64 + n*16 + lr;
        C[row*ldc + col] = (T)acc[m][n][i];
      }
    }
}

// ---------------- fused dual-acc GEMM + modulation epilogue, 8-wave 128x128 tile ----------------
// Counted-vmcnt pipeline (T4): tiles t,t+1 always in flight; vmcnt(4) waits ONLY the
// oldest 4 loads (tile t); raw s_barrier (no vmcnt(0) drain in the main loop).
// [Session-best of 6 schedule variants: 361us, VGPR 64, 43% occ.] gates bf16.
__global__ __launch_bounds__(512, 4) void gemm_fused2_k(const bf16_t* __restrict__ A,
                                                        const bf16_t* __restrict__ Wt,   // [8192][3072]
                                                        const bf16_t* __restrict__ Zbig,
                                                        const bf16_t* __restrict__ Wbig,
                                                        bf16_t* __restrict__ gates) {
  __shared__ bf16_t sA[2*128*64];
  __shared__ bf16_t sB[2*128*64];
  const int tid = threadIdx.x;
  const int wave = tid >> 6, lane = tid & 63;
  const int tm = blockIdx.y * 128, tn = blockIdx.x * 128;
  const int wm = wave >> 2, wn = wave & 3;
  const int lq = lane >> 4, lr = lane & 15;

  const bf16_t* Ab = A  + (long)tm * 3200;
  const bf16_t* Bb = Wt + (long)tn * 3072;

  f32x4 accX[4][2], accH[4][2];
  #pragma unroll
  for (int m = 0; m < 4; ++m)
    #pragma unroll
    for (int n = 0; n < 2; ++n) { f32x4 zv = {0.f,0.f,0.f,0.f}; accX[m][n] = zv; accH[m][n] = zv; }

  int rowS[2], kofS[2], ldsoff[2];
  #pragma unroll
  for (int c = 0; c < 2; ++c) {
    int ci = c*512 + tid;
    int row = ci >> 3, kcp = ci & 7;
    int kcl = kcp ^ (row & 7);           // pre-swizzled source chunk
    rowS[c] = row; kofS[c] = kcl * 8;
    ldsoff[c] = (c*512 + wave*64) * 8;   // wave-uniform element offset
  }

#define F_STAGE(BUF, K0)                                                            \
  { const int k0 = (K0);                                                            \
    _Pragma("unroll")                                                               \
    for (int c = 0; c < 2; ++c) {                                                   \
      glds16(Ab + (long)rowS[c]*3200 + k0 + kofS[c], sA + (BUF)*8192 + ldsoff[c]);  \
      glds16(Bb + (long)rowS[c]*3072 + k0 + kofS[c], sB + (BUF)*8192 + ldsoff[c]);  \
    } }

#define F_COMPUTE(BUF, ACC)                                                         \
  { const bf16_t* aB = sA + (BUF)*8192;                                             \
    const bf16_t* bB = sB + (BUF)*8192;                                             \
    _Pragma("unroll")                                                               \
    for (int kk = 0; kk < 64; kk += 32) {                                           \
      const int kc = (kk >> 3) + lq;                                                \
      bf16x8 af[4], bfr[2];                                                         \
      _Pragma("unroll")                                                             \
      for (int m = 0; m < 4; ++m) {                                                 \
        int row = wm*64 + m*16 + lr;                                                \
        af[m] = *(const bf16x8*)(aB + row*64 + ((kc ^ (row & 7)) << 3));            \
      }                                                                             \
      _Pragma("unroll")                                                             \
      for (int n = 0; n < 2; ++n) {                                                 \
        int row = wn*32 + n*16 + lr;                                                \
        bfr[n] = *(const bf16x8*)(bB + row*64 + ((kc ^ (row & 7)) << 3));           \
      }                                                                             \
      _Pragma("unroll")                                                             \
      for (int m = 0; m < 4; ++m)                                                   \
        _Pragma("unroll")                                                           \
        for (int n = 0; n < 2; ++n)                                                 \
          ACC[m][n] = __builtin_amdgcn_mfma_f32_16x16x32_bf16(af[m], bfr[n], ACC[m][n], 0, 0, 0); \
    } }

#define WAITV4 asm volatile("s_waitcnt vmcnt(4)" ::: "memory")
#define WAITV0 asm volatile("s_waitcnt vmcnt(0)" ::: "memory")
#define BAR()  __builtin_amdgcn_s_barrier()

  int cur = 0;
  F_STAGE(0, 0)
  F_STAGE(1, 64)
  // X phase: kt = 0..15 (kt+2 <= 17 < 48, always stage)
  for (int kt = 0; kt < 16; ++kt) {
    WAITV4;                      // tile kt's 4 loads done (oldest of 8)
    BAR();
    F_COMPUTE(cur, accX)
    BAR();
    F_STAGE(cur, (kt + 2) << 6)  // overwrite buf read this iter (safe after barrier)
    cur ^= 1;
  }
  // H phase: kt = 16..47
  for (int kt = 16; kt < 48; ++kt) {
    if (kt < 47) { WAITV4; } else { WAITV0; }
    BAR();
    F_COMPUTE(cur, accH)
    BAR();
    if (kt + 2 < 48) F_STAGE(cur, (kt + 2) << 6)
    cur ^= 1;
  }
#undef F_STAGE
#undef F_COMPUTE
#undef WAITV4
#undef WAITV0
#undef BAR

  // ---- modulation epilogue (Z frags reloaded per-n to cap register liveness) ----
  const int g   = tn >> 11;       // gate index (tile lies within one gate; 256|2048)
  const int cg0 = tn & 2047;      // col offset within gate
  #pragma unroll
  for (int m = 0; m < 4; ++m) {
    const bf16_t* Zr = Zbig + ((long)g*4096 + tm + wm*64 + m*16 + lr) * 256;
    #pragma unroll
    for (int n = 0; n < 2; ++n) {
      const bf16_t* Wc = Wbig + ((long)g*2048 + cg0 + wn*32 + n*16 + lr) * 256;
      f32x4 aX = {0.f,0.f,0.f,0.f};
      f32x4 aH = {0.f,0.f,0.f,0.f};
      f32x4 aC = {0.f,0.f,0.f,0.f};
      {  // X scale: kstep0 (hi*hi + hi*lo + lo*hi)
        bf16x8 zh = *(const bf16x8*)(Zr + 0*32 + lq*8);
        bf16x8 zl = *(const bf16x8*)(Zr + 128 + 0*32 + lq*8);
        bf16x8 wh = *(const bf16x8*)(Wc + 0*32 + lq*8);
        bf16x8 wl = *(const bf16x8*)(Wc + 128 + 0*32 + lq*8);
        aX = __builtin_amdgcn_mfma_f32_16x16x32_bf16(zh, wh, aX, 0,0,0);
        aX = __builtin_amdgcn_mfma_f32_16x16x32_bf16(zh, wl, aX, 0,0,0);
        aX = __builtin_amdgcn_mfma_f32_16x16x32_bf16(zl, wh, aX, 0,0,0);
      }
      {  // H scale: kstep1
        bf16x8 zh = *(const bf16x8*)(Zr + 1*32 + lq*8);
        bf16x8 zl = *(const bf16x8*)(Zr + 128 + 1*32 + lq*8);
        bf16x8 wh = *(const bf16x8*)(Wc + 1*32 + lq*8);
        bf16x8 wl = *(const bf16x8*)(Wc + 128 + 1*32 + lq*8);
        aH = __builtin_amdgcn_mfma_f32_16x16x32_bf16(zh, wh, aH, 0,0,0);
        aH = __builtin_amdgcn_mfma_f32_16x16x32_bf16(zh, wl, aH, 0,0,0);
        aH = __builtin_amdgcn_mfma_f32_16x16x32_bf16(zl, wh, aH, 0,0,0);
      }
      {  // C offset: ksteps 2,3
        bf16x8 zh = *(const bf16x8*)(Zr + 2*32 + lq*8);
        bf16x8 zl = *(const bf16x8*)(Zr + 128 + 2*32 + lq*8);
        bf16x8 wh = *(const bf16x8*)(Wc + 2*32 + lq*8);
        bf16x8 wl = *(const bf16x8*)(Wc + 128 + 2*32 + lq*8);
        aC = __builtin_amdgcn_mfma_f32_16x16x32_bf16(zh, wh, aC, 0,0,0);
        aC = __builtin_amdgcn_mfma_f32_16x16x32_bf16(zh, wl, aC, 0,0,0);
        aC = __builtin_amdgcn_mfma_f32_16x16x32_bf16(zl, wh, aC, 0,0,0);
        zh = *(const bf16x8*)(Zr + 3*32 + lq*8);
        zl = *(const bf16x8*)(Zr + 128 + 3*32 + lq*8);
        wh = *(const bf16x8*)(Wc + 3*32 + lq*8);
        wl = *(const bf16x8*)(Wc + 128 + 3*32 + lq*8);
        aC = __builtin_amdgcn_mfma_f32_16x16x32_bf16(zh, wh, aC, 0,0,0);
        aC = __builtin_amdgcn_mfma_f32_16x16x32_bf16(zh, wl, aC, 0,0,0);
        aC = __builtin_amdgcn_mfma_f32_16x16x32_bf16(zl, wh, aC, 0,0,0);
      }
      #pragma unroll
      for (int i = 0; i < 4; ++i) {
        long row = tm + wm*64 + m*16 + lq*4 + i;
        long col = (long)tn + wn*32 + n*16 + lr;
        gates[row*8192 + col] = (bf16_t)(aX[i]*accX[m][n][i] + aH[i]*accH[m][n][i] + aC[i]);
      }
    }
  }
}

// ---------------- hyper LSTM cell: 1 wave per batch row; sums 5 split-K partials ----------------
__global__ __launch_bounds__(64) void hyper_cell_k(const float* __restrict__ hcat_part,
                                                   const float* __restrict__ tc,
                                                   const float* __restrict__ h_bias,
                                                   const float* __restrict__ hg, const float* __restrict__ hb,
                                                   const float* __restrict__ hcg, const float* __restrict__ hcb,
                                                   float* __restrict__ out, float* __restrict__ hout) {
  const int b = blockIdx.x, l = threadIdx.x;
  const int u0 = 2 * l;
  float v[4][2], nv[4][2];
  #pragma unroll
  for (int g = 0; g < 4; ++g)
    #pragma unroll
    for (int p = 0; p < 2; ++p) {
      long idx = (long)b*512 + g*128 + u0 + p;
      float s = h_bias[g*128 + u0 + p];
      #pragma unroll
      for (int z = 0; z < 5; ++z) s += hcat_part[z*2097152L + idx];
      v[g][p] = s;
    }
  #pragma unroll
  for (int g = 0; g < 4; ++g) {
    float s = v[g][0] + v[g][1];
    float q = v[g][0]*v[g][0] + v[g][1]*v[g][1];
    #pragma unroll
    for (int m = 32; m >= 1; m >>= 1) { s += __shfl_xor(s, m); q += __shfl_xor(q, m); }
    float mean = s * (1.0f/128.0f);
    float inv = rsqrtf(q * (1.0f/128.0f) - mean*mean + EPS);
    #pragma unroll
    for (int p = 0; p < 2; ++p)
      nv[g][p] = (v[g][p] - mean) * inv * hg[g*128 + u0 + p] + hb[g*128 + u0 + p];
  }
  float nc[2], oo[2];
  #pragma unroll
  for (int p = 0; p < 2; ++p) {
    float ii = sigmoidf_(nv[0][p]);
    float jj = tanhf_(nv[1][p]);
    float ff = sigmoidf_(nv[2][p] + 1.0f);
    oo[p] = sigmoidf_(nv[3][p]);
    float hc = tc[(long)b*2176 + 2048 + u0 + p];
    nc[p] = hc * ff + ii * jj;
  }
  float s = nc[0] + nc[1], q = nc[0]*nc[0] + nc[1]*nc[1];
  #pragma unroll
  for (int m = 32; m >= 1; m >>= 1) { s += __shfl_xor(s, m); q += __shfl_xor(q, m); }
  float mean = s * (1.0f/128.0f);
  float inv = rsqrtf(q * (1.0f/128.0f) - mean*mean + EPS);
  #pragma unroll
  for (int p = 0; p < 2; ++p) {
    float nh = tanhf_((nc[p] - mean) * inv * hcg[u0 + p] + hcb[u0 + p]) * oo[p];
    out[OUT1 + (long)b*2176 + 2048 + u0 + p] = nc[p];
    out[OUT2 + (long)b*2176 + 2048 + u0 + p] = nh;
    hout[(long)b*128 + u0 + p] = nh;
  }
}

// ---------------- zhyper: zw/zb dots -> Zbig[4][4096][2][128] bf16 hi/lo ----------------
// 16 batch rows per block (256 blocks): weights stream once per 16 rows.
__global__ __launch_bounds__(192) void zhyper_k(const float* __restrict__ hout,
                                                const float* __restrict__ zwW, const float* __restrict__ zbias,
                                                const float* __restrict__ zbW,
                                                bf16_t* __restrict__ Zbig) {
  const int r0 = blockIdx.x * 16;
  const int t = threadIdx.x;
  __shared__ float ho[16][128];
  for (int i = t; i < 2048; i += 192) {
    int r = i >> 7, u = i & 127;
    ho[r][u] = hout[(long)(r0 + r)*128 + u];
  }
  // zero-fill pad segs 1,3 for all 4 gates (hi+lo) for these 16 rows
  if (t < 128) {
    int zg = t >> 5, zs = 1 + 2*((t >> 4) & 1), ze = t & 15;
    #pragma unroll
    for (int r = 0; r < 16; ++r) {
      long zbase = ((long)(zg*4096) + r0 + r)*256 + zs*16 + ze;
      Zbig[zbase] = (bf16_t)0.f; Zbig[zbase + 128] = (bf16_t)0.f;
    }
  }
  __syncthreads();
  const int k = t >> 4, e = t & 15;
  const float* wp = zwW + (long)k*2048 + e;
  const float* bp = zbW + (long)k*2048 + e;
  float a[16], a2[16];
  #pragma unroll
  for (int r = 0; r < 16; ++r) { a[r] = 0.f; a2[r] = 0.f; }
  for (int u0 = 0; u0 < 128; u0 += 8) {
    float wv[8], bv[8];
    #pragma unroll
    for (int j = 0; j < 8; ++j) { wv[j] = wp[(u0 + j)*16]; bv[j] = bp[(u0 + j)*16]; }
    #pragma unroll
    for (int r = 0; r < 16; ++r) {
      #pragma unroll
      for (int j = 0; j < 8; ++j) {
        float h = ho[r][u0 + j];
        a[r]  += h * wv[j];
        a2[r] += h * bv[j];
      }
    }
  }
  const float zb0 = zbias[k*16 + e];
  const int g = k & 3, kk = k >> 2;
  const int segA = kk*2;      // 0,2,4
  const int segB = kk + 5;    // 5,6,7
  #pragma unroll
  for (int r = 0; r < 16; ++r) {
    float av = a[r] + zb0;
    long baseg = ((long)(g*4096) + r0 + r)*256;
    bf16_t ah = (bf16_t)av;
    Zbig[baseg + segA*16 + e]       = ah;
    Zbig[baseg + 128 + segA*16 + e] = (bf16_t)(av - (float)ah);
    bf16_t bh = (bf16_t)a2[r];
    Zbig[baseg + segB*16 + e]       = bh;
    Zbig[baseg + 128 + segB*16 + e] = (bf16_t)(a2[r] - (float)bh);
  }
}

// ---------------- wbig: pack weights -> Wbig[4][2048][2][128] bf16 hi/lo (bias folded at seg 4) ----------------
__global__ __launch_bounds__(256) void wbig_k(const float* __restrict__ ww,
                                              const float* __restrict__ bw,
                                              const float* __restrict__ bias,
                                              bf16_t* __restrict__ Wbig) {
  int idx = blockIdx.x * 256 + threadIdx.x;   // 4*2048*16 = 131072 chunks of 8 k
  int c = idx & 15;
  int j = (idx >> 4) & 2047;
  int g = idx >> 15;
  int k0 = c * 8, seg = k0 >> 4, e0 = k0 & 15;
  float v[8];
  for (int u = 0; u < 8; ++u) v[u] = 0.f;
  if (seg == 0) {
    for (int u = 0; u < 8; ++u) v[u] = ww[(long)((g*16) + e0 + u)*2048 + j];
  } else if (seg == 2) {
    for (int u = 0; u < 8; ++u) v[u] = ww[(long)(((4+g)*16) + e0 + u)*2048 + j];
  } else if (seg == 4) {
    float bc = bias[g*2048 + j];
    for (int u = 0; u < 8; ++u) v[u] = ww[(long)(((8+g)*16) + e0 + u)*2048 + j] * bc;
  } else if (seg == 5) {
    for (int u = 0; u < 8; ++u) v[u] = bw[(long)((g*16) + e0 + u)*2048 + j];
  } else if (seg == 6) {
    for (int u = 0; u < 8; ++u) v[u] = bw[(long)(((4+g)*16) + e0 + u)*2048 + j];
  } else if (seg == 7) {
    for (int u = 0; u < 8; ++u) v[u] = bw[(long)(((8+g)*16) + e0 + u)*2048 + j];
  }
  bf16x8 hi, lo;
  for (int u = 0; u < 8; ++u) {
    bf16_t h = (bf16_t)v[u];
    hi[u] = h; lo[u] = (bf16_t)(v[u] - (float)h);
  }
  long base = ((long)(g*2048) + j)*256 + k0;
  *(bf16x8*)(Wbig + base)       = hi;
  *(bf16x8*)(Wbig + base + 128) = lo;
}

// ---------------- M2: main cell — 4 gate-LNs, LSTM update, c-LN, outputs (bf16 gates in) ----------------
__global__ __launch_bounds__(256) void cell_main_k(const bf16_t* __restrict__ gates,
                                                   const float* __restrict__ tc,
                                                   const float* __restrict__ lng, const float* __restrict__ lnb,
                                                   const float* __restrict__ lcg, const float* __restrict__ lcb,
                                                   float* __restrict__ out) {
  const int b = blockIdx.x, t = threadIdx.x;
  const int wave = t >> 6, lane = t & 63;
  const int j0 = t * 8;
  float gv[4][8], s[4], q[4];
  #pragma unroll
  for (int g = 0; g < 4; ++g) {
    bf16x8 v = *(const bf16x8*)(gates + (long)b*8192 + g*2048 + j0);
    float ls = 0.f, lq = 0.f;
    #pragma unroll
    for (int u = 0; u < 8; ++u) { float f = (float)v[u]; gv[g][u] = f; ls += f; lq += f*f; }
    s[g] = ls; q[g] = lq;
  }
  #pragma unroll
  for (int g = 0; g < 4; ++g)
    #pragma unroll
    for (int m = 32; m >= 1; m >>= 1) { s[g] += __shfl_xor(s[g], m); q[g] += __shfl_xor(q[g], m); }
  __shared__ float red[4][4][2];
  if (lane == 0) {
    #pragma unroll
    for (int g = 0; g < 4; ++g) { red[g][wave][0] = s[g]; red[g][wave][1] = q[g]; }
  }
  __syncthreads();
  float mean[4], inv[4];
  #pragma unroll
  for (int g = 0; g < 4; ++g) {
    float S = red[g][0][0] + red[g][1][0] + red[g][2][0] + red[g][3][0];
    float Q = red[g][0][1] + red[g][1][1] + red[g][2][1] + red[g][3][1];
    float m = S * (1.0f/2048.0f);
    mean[g] = m; inv[g] = rsqrtf(Q * (1.0f/2048.0f) - m*m + EPS);
  }
  float nc[8], oo[8];
  const float* cb = tc + (long)b*2176;
  #pragma unroll
  for (int u = 0; u < 8; ++u) {
    int j = j0 + u;
    float iv = (gv[0][u] - mean[0]) * inv[0] * lng[j]        + lnb[j];
    float jv = (gv[1][u] - mean[1]) * inv[1] * lng[2048 + j] + lnb[2048 + j];
    float fv = (gv[2][u] - mean[2]) * inv[2] * lng[4096 + j] + lnb[4096 + j];
    float ov = (gv[3][u] - mean[3]) * inv[3] * lng[6144 + j] + lnb[6144 + j];
    nc[u] = cb[j] * sigmoidf_(fv + 1.0f) + sigmoidf_(iv) * tanhf_(jv);
    oo[u] = sigmoidf_(ov);
  }
  float s2 = 0.f, q2 = 0.f;
  #pragma unroll
  for (int u = 0; u < 8; ++u) { s2 += nc[u]; q2 += nc[u]*nc[u]; }
  #pragma unroll
  for (int m = 32; m >= 1; m >>= 1) { s2 += __shfl_xor(s2, m); q2 += __shfl_xor(q2, m); }
  __syncthreads();
  if (lane == 0) { red[0][wave][0] = s2; red[0][wave][1] = q2; }
  __syncthreads();
  float S2 = red[0][0][0] + red[0][1][0] + red[0][2][0] + red[0][3][0];
  float Q2 = red[0][0][1] + red[0][1][1] + red[0][2][1] + red[0][3][1];
  float mc = S2 * (1.0f/2048.0f);
  float ic = rsqrtf(Q2 * (1.0f/2048.0f) - mc*mc + EPS);
  float nh[8];
  #pragma unroll
  for (int u = 0; u < 8; ++u)
    nh[u] = tanhf_((nc[u] - mc) * ic * lcg[j0 + u] + lcb[j0 + u]) * oo[u];
  float4 h0 = make_float4(nh[0], nh[1], nh[2], nh[3]);
  float4 h1 = make_float4(nh[4], nh[5], nh[6], nh[7]);
  float4 c0 = make_float4(nc[0], nc[1], nc[2], nc[3]);
  float4 c1 = make_float4(nc[4], nc[5], nc[6], nc[7]);
  *(float4*)(out + (long)b*2048 + j0)            = h0;
  *(float4*)(out + (long)b*2048 + j0 + 4)        = h1;
  *(float4*)(out + OUT1 + (long)b*2176 + j0)     = c0;
  *(float4*)(out + OUT1 + (long)b*2176 + j0 + 4) = c1;
  *(float4*)(out + OUT2 + (long)b*2176 + j0)     = h0;
  *(float4*)(out + OUT2 + (long)b*2176 + j0 + 4) = h1;
}

extern "C" void kernel_launch(void* const* d_in, const int* in_sizes, int n_in,
                              void* d_out, int out_size, void* d_ws, size_t ws_size,
                              hipStream_t stream) {
  const float* x      = (const float*)d_in[0];
  const float* tc     = (const float*)d_in[1];
  const float* th     = (const float*)d_in[2];
  const float* W_xh   = (const float*)d_in[3];
  const float* W_hh   = (const float*)d_in[4];
  const float* bias   = (const float*)d_in[5];
  const float* ln_g   = (const float*)d_in[6];
  const float* ln_b   = (const float*)d_in[7];
  const float* lnc_g  = (const float*)d_in[8];
  const float* lnc_b  = (const float*)d_in[9];
  const float* hW_xh  = (const float*)d_in[10];
  const float* hW_hh  = (const float*)d_in[11];
  const float* h_bias = (const float*)d_in[12];
  const float* h_ln_g = (const float*)d_in[13];
  const float* h_ln_b = (const float*)d_in[14];
  const float* h_lnc_g= (const float*)d_in[15];
  const float* h_lnc_b= (const float*)d_in[16];
  const float* hyp_zw = (const float*)d_in[17];
  const float* hyp_zb = (const float*)d_in[18];
  const float* hyp_ww = (const float*)d_in[19];
  const float* hyp_zbw= (const float*)d_in[20];
  const float* hyp_bw = (const float*)d_in[21];
  float* out = (float*)d_out;

  // Workspace layout. Total ~191 MB (gates bf16).
  char* w = (char*)d_ws;
  bf16_t* A        = (bf16_t*)w;  w += 4096L*3200*2;   //  26,214,400
  bf16_t* WtALL    = (bf16_t*)w;  w += 8192L*3072*2;   //  50,331,648
  bf16_t* WtCAT    = (bf16_t*)w;  w += 512L*3200*2;    //   3,276,800
  float*  hcat_part= (float*)w;   w += 5L*4096*512*4;  //  41,943,040
  float*  hout     = (float*)w;   w += 4096L*128*4;    //   2,097,152
  bf16_t* Zbig     = (bf16_t*)w;  w += 4L*4096*256*2;  //   8,388,608
  bf16_t* Wbig     = (bf16_t*)w;  w += 4L*2048*256*2;  //   4,194,304
  bf16_t* gates    = (bf16_t*)w;  w += 4096L*8192*2;   //  67,108,864

  build_A_k<<<2048, 256, 0, stream>>>(x, th, A);
  transpose_conv_k<<<dim3(256, 96),  dim3(32, 8), 0, stream>>>(W_xh, 1024, W_hh, 3072, 8192, WtALL);
  transpose_conv_k<<<dim3(16, 100),  dim3(32, 8), 0, stream>>>(hW_xh, 3072, hW_hh, 3200, 512, WtCAT);
  gemm_bf16_k<float><<<dim3(4, 32, 5), 256, 0, stream>>>(A, 3200, WtCAT, 3200, hcat_part, 512, 640, 4096L*512);
  hyper_cell_k<<<4096, 64, 0, stream>>>(hcat_part, tc, h_bias, h_ln_g, h_ln_b, h_lnc_g, h_lnc_b, out, hout);
  zhyper_k<<<256, 192, 0, stream>>>(hout, hyp_zw, hyp_zb, hyp_zbw, Zbig);
  wbig_k<<<512, 256, 0, stream>>>(hyp_ww, hyp_bw, bias, Wbig);
  gemm_fused2_k<<<dim3(64, 32), 512, 0, stream>>>(A, WtALL, Zbig, Wbig, gates);
  cell_main_k<<<4096, 256, 0, stream>>>(gates, tc, ln_g, ln_b, lnc_g, lnc_b, out);
}

// Round 19
// 511.554 us; speedup vs baseline: 1.6766x; 1.0172x over previous
//
#include <hip/hip_runtime.h>

typedef __bf16 bf16_t;
typedef __attribute__((ext_vector_type(8))) __bf16 bf16x8;
typedef __attribute__((ext_vector_type(4))) __bf16 bf16x4;
typedef __attribute__((ext_vector_type(4))) float f32x4;

#define EPS 1e-3f
#define OUT1 (4096L*2048)
#define OUT2 (OUT1 + 4096L*2176)

// Fast transcendentals via HW v_exp_f32 (rel err ~1e-6 << bf16 tolerance).
__device__ __forceinline__ float sigmoidf_(float x){ return 1.0f/(1.0f+__expf(-x)); }
__device__ __forceinline__ float tanhf_(float x){
  float e = __expf(-2.0f*fabsf(x));          // e in (0,1]; no overflow
  float r = (1.0f - e)/(1.0f + e);
  return copysignf(r, x);
}

__device__ __forceinline__ void glds16(const void* g, void* l) {
  __builtin_amdgcn_global_load_lds(
      (__attribute__((address_space(1))) void*)g,
      (__attribute__((address_space(3))) void*)l, 16, 0, 0);
}

// ---------------- build A = [x | h | hyper_h] as bf16, [4096][3200] ----------------
__global__ __launch_bounds__(256) void build_A_k(const float* __restrict__ x,
                                                 const float* __restrict__ th,
                                                 bf16_t* __restrict__ A) {
  const int total = 4096 * 800;  // groups of 4 elements
  for (int i = blockIdx.x * blockDim.x + threadIdx.x; i < total; i += gridDim.x * blockDim.x) {
    int b = i / 800;
    int c4 = (i - b * 800) * 4;
    float4 v;
    if (c4 < 1024)       v = *(const float4*)(x  + (long)b*1024 + c4);
    else if (c4 < 3072)  v = *(const float4*)(th + (long)b*2176 + (c4 - 1024));
    else                 v = *(const float4*)(th + (long)b*2176 + 2048 + (c4 - 3072));
    bf16x4 o = { (bf16_t)v.x, (bf16_t)v.y, (bf16_t)v.z, (bf16_t)v.w };
    *(bf16x4*)(A + (long)i*4) = o;
  }
}

// ---------------- transpose + convert: in fp32 [K][N] (split at K1) -> out bf16 [N][Ktot] ----------------
__global__ __launch_bounds__(256) void transpose_conv_k(const float* __restrict__ in1, int K1,
                                                        const float* __restrict__ in2, int Ktot,
                                                        int N, bf16_t* __restrict__ out) {
  __shared__ float tile[32][33];
  int n0 = blockIdx.x * 32, k0 = blockIdx.y * 32;
  int tx = threadIdx.x, ty = threadIdx.y;  // (32,8)
  #pragma unroll
  for (int r = 0; r < 4; ++r) {
    int k = k0 + ty + r*8;
    float v = (k < K1) ? in1[(long)k*N + n0 + tx] : in2[(long)(k - K1)*N + n0 + tx];
    tile[ty + r*8][tx] = v;
  }
  __syncthreads();
  #pragma unroll
  for (int r = 0; r < 4; ++r) {
    int n = n0 + ty + r*8;
    out[(long)n*Ktot + k0 + tx] = (bf16_t)tile[tx][ty + r*8];
  }
}

// ---------------- bf16 GEMM, split-K via blockIdx.z, 2-phase LDS double-buffer ----------------
template<typename T>
__global__ __launch_bounds__(256) void gemm_bf16_k(const bf16_t* __restrict__ A, int lda,
                                                   const bf16_t* __restrict__ Bt, int ldb,
                                                   T* __restrict__ C, int ldc, int K,
                                                   long coutStride) {
  const int z = blockIdx.z;
  A  += (long)z * K;
  Bt += (long)z * K;
  C  += (long)z * coutStride;
  __shared__ bf16_t sA[2*128*64];
  __shared__ bf16_t sB[2*128*64];
  const int tid = threadIdx.x;
  const int wave = tid >> 6, lane = tid & 63;
  const int tm = blockIdx.y * 128, tn = blockIdx.x * 128;
  const int wm = wave >> 1, wn = wave & 1;
  const int lq = lane >> 4, lr = lane & 15;

  const bf16_t* Ab = A + (long)tm * lda;
  const bf16_t* Bb = Bt + (long)tn * ldb;

  f32x4 acc[4][4];
  #pragma unroll
  for (int m = 0; m < 4; ++m)
    #pragma unroll
    for (int n = 0; n < 4; ++n) { f32x4 zv = {0.f,0.f,0.f,0.f}; acc[m][n] = zv; }

  int rowS[4], kofS[4], ldsoff[4];
  #pragma unroll
  for (int c = 0; c < 4; ++c) {
    int ci = c*256 + tid;
    int row = ci >> 3, kcp = ci & 7;
    int kcl = kcp ^ (row & 7);           // pre-swizzled source chunk
    rowS[c] = row; kofS[c] = kcl * 8;
    ldsoff[c] = (c*256 + wave*64) * 8;   // wave-uniform element offset
  }

#define H_STAGE(BUF, K0)                                                          \
  { const int k0 = (K0);                                                          \
    _Pragma("unroll")                                                             \
    for (int c = 0; c < 4; ++c) {                                                 \
      glds16(Ab + (long)rowS[c]*lda + k0 + kofS[c], sA + (BUF)*8192 + ldsoff[c]); \
      glds16(Bb + (long)rowS[c]*ldb + k0 + kofS[c], sB + (BUF)*8192 + ldsoff[c]); \
    } }

  const int nk = K >> 6;
  int cur = 0;
  H_STAGE(0, 0)
  __syncthreads();
  for (int kt = 0; kt < nk; ++kt) {
    if (kt + 1 < nk) H_STAGE(cur ^ 1, (kt + 1) << 6)
    const bf16_t* aB = sA + cur*8192;
    const bf16_t* bB = sB + cur*8192;
    #pragma unroll
    for (int kk = 0; kk < 64; kk += 32) {
      const int kc = (kk >> 3) + lq;
      bf16x8 af[4], bf[4];
      #pragma unroll
      for (int m = 0; m < 4; ++m) {
        int row = wm*64 + m*16 + lr;
        af[m] = *(const bf16x8*)(aB + row*64 + ((kc ^ (row & 7)) << 3));
      }
      #pragma unroll
      for (int n = 0; n < 4; ++n) {
        int row = wn*64 + n*16 + lr;
        bf[n] = *(const bf16x8*)(bB + row*64 + ((kc ^ (row & 7)) << 3));
      }
      #pragma unroll
      for (int m = 0; m < 4; ++m)
        #pragma unroll
        for (int n = 0; n < 4; ++n)
          acc[m][n] = __builtin_amdgcn_mfma_f32_16x16x32_bf16(af[m], bf[n], acc[m][n], 0, 0, 0);
    }
    __syncthreads();
    cur ^= 1;
  }
#undef H_STAGE

  // epilogue: C/D layout col=lane&15, row=(lane>>4)*4+i
  #pragma unroll
  for (int m = 0; m < 4; ++m)
    #pragma unroll
    for (int i = 0; i < 4; ++i) {
      long row = tm + wm*64 + m*16 + lq*4 + i;
      #pragma unroll
      for (int n = 0; n < 4; ++n) {
        int col = tn + wn*64 + n*16 + lr;
        C[row*ldc + col] = (T)acc[m][n][i];
      }
    }
}

// ---------------- fused dual-acc GEMM + modulation epilogue, 8-wave 128x128 tile ----------------
// Counted-vmcnt pipeline (T4): tiles t,t+1 always in flight; vmcnt(4) waits ONLY the
// oldest 4 loads (tile t); raw s_barrier (no vmcnt(0) drain in the main loop).
// [Session-best of 6 schedule variants: ~361us, VGPR 64, 43% occ.] gates bf16.
__global__ __launch_bounds__(512, 4) void gemm_fused2_k(const bf16_t* __restrict__ A,
                                                        const bf16_t* __restrict__ Wt,   // [8192][3072]
                                                        const bf16_t* __restrict__ Zbig,
                                                        const bf16_t* __restrict__ Wbig,
                                                        bf16_t* __restrict__ gates) {
  __shared__ bf16_t sA[2*128*64];
  __shared__ bf16_t sB[2*128*64];
  const int tid = threadIdx.x;
  const int wave = tid >> 6, lane = tid & 63;
  const int tm = blockIdx.y * 128, tn = blockIdx.x * 128;
  const int wm = wave >> 2, wn = wave & 3;
  const int lq = lane >> 4, lr = lane & 15;

  const bf16_t* Ab = A  + (long)tm * 3200;
  const bf16_t* Bb = Wt + (long)tn * 3072;

  f32x4 accX[4][2], accH[4][2];
  #pragma unroll
  for (int m = 0; m < 4; ++m)
    #pragma unroll
    for (int n = 0; n < 2; ++n) { f32x4 zv = {0.f,0.f,0.f,0.f}; accX[m][n] = zv; accH[m][n] = zv; }

  int rowS[2], kofS[2], ldsoff[2];
  #pragma unroll
  for (int c = 0; c < 2; ++c) {
    int ci = c*512 + tid;
    int row = ci >> 3, kcp = ci & 7;
    int kcl = kcp ^ (row & 7);           // pre-swizzled source chunk
    rowS[c] = row; kofS[c] = kcl * 8;
    ldsoff[c] = (c*512 + wave*64) * 8;   // wave-uniform element offset
  }

#define F_STAGE(BUF, K0)                                                            \
  { const int k0 = (K0);                                                            \
    _Pragma("unroll")                                                               \
    for (int c = 0; c < 2; ++c) {                                                   \
      glds16(Ab + (long)rowS[c]*3200 + k0 + kofS[c], sA + (BUF)*8192 + ldsoff[c]);  \
      glds16(Bb + (long)rowS[c]*3072 + k0 + kofS[c], sB + (BUF)*8192 + ldsoff[c]);  \
    } }

#define F_COMPUTE(BUF, ACC)                                                         \
  { const bf16_t* aB = sA + (BUF)*8192;                                             \
    const bf16_t* bB = sB + (BUF)*8192;                                             \
    _Pragma("unroll")                                                               \
    for (int kk = 0; kk < 64; kk += 32) {                                           \
      const int kc = (kk >> 3) + lq;                                                \
      bf16x8 af[4], bfr[2];                                                         \
      _Pragma("unroll")                                                             \
      for (int m = 0; m < 4; ++m) {                                                 \
        int row = wm*64 + m*16 + lr;                                                \
        af[m] = *(const bf16x8*)(aB + row*64 + ((kc ^ (row & 7)) << 3));            \
      }                                                                             \
      _Pragma("unroll")                                                             \
      for (int n = 0; n < 2; ++n) {                                                 \
        int row = wn*32 + n*16 + lr;                                                \
        bfr[n] = *(const bf16x8*)(bB + row*64 + ((kc ^ (row & 7)) << 3));           \
      }                                                                             \
      _Pragma("unroll")                                                             \
      for (int m = 0; m < 4; ++m)                                                   \
        _Pragma("unroll")                                                           \
        for (int n = 0; n < 2; ++n)                                                 \
          ACC[m][n] = __builtin_amdgcn_mfma_f32_16x16x32_bf16(af[m], bfr[n], ACC[m][n], 0, 0, 0); \
    } }

#define WAITV4 asm volatile("s_waitcnt vmcnt(4)" ::: "memory")
#define WAITV0 asm volatile("s_waitcnt vmcnt(0)" ::: "memory")
#define BAR()  __builtin_amdgcn_s_barrier()

  int cur = 0;
  F_STAGE(0, 0)
  F_STAGE(1, 64)
  // X phase: kt = 0..15 (kt+2 <= 17 < 48, always stage)
  for (int kt = 0; kt < 16; ++kt) {
    WAITV4;                      // tile kt's 4 loads done (oldest of 8)
    BAR();
    F_COMPUTE(cur, accX)
    BAR();
    F_STAGE(cur, (kt + 2) << 6)  // overwrite buf read this iter (safe after barrier)
    cur ^= 1;
  }
  // H phase: kt = 16..47
  for (int kt = 16; kt < 48; ++kt) {
    if (kt < 47) { WAITV4; } else { WAITV0; }
    BAR();
    F_COMPUTE(cur, accH)
    BAR();
    if (kt + 2 < 48) F_STAGE(cur, (kt + 2) << 6)
    cur ^= 1;
  }
#undef F_STAGE
#undef F_COMPUTE
#undef WAITV4
#undef WAITV0
#undef BAR

  // ---- modulation epilogue (Z frags reloaded per-n to cap register liveness) ----
  const int g   = tn >> 11;       // gate index (tile lies within one gate; 256|2048)
  const int cg0 = tn & 2047;      // col offset within gate
  #pragma unroll
  for (int m = 0; m < 4; ++m) {
    const bf16_t* Zr = Zbig + ((long)g*4096 + tm + wm*64 + m*16 + lr) * 256;
    #pragma unroll
    for (int n = 0; n < 2; ++n) {
      const bf16_t* Wc = Wbig + ((long)g*2048 + cg0 + wn*32 + n*16 + lr) * 256;
      f32x4 aX = {0.f,0.f,0.f,0.f};
      f32x4 aH = {0.f,0.f,0.f,0.f};
      f32x4 aC = {0.f,0.f,0.f,0.f};
      {  // X scale: kstep0 (hi*hi + hi*lo + lo*hi)
        bf16x8 zh = *(const bf16x8*)(Zr + 0*32 + lq*8);
        bf16x8 zl = *(const bf16x8*)(Zr + 128 + 0*32 + lq*8);
        bf16x8 wh = *(const bf16x8*)(Wc + 0*32 + lq*8);
        bf16x8 wl = *(const bf16x8*)(Wc + 128 + 0*32 + lq*8);
        aX = __builtin_amdgcn_mfma_f32_16x16x32_bf16(zh, wh, aX, 0,0,0);
        aX = __builtin_amdgcn_mfma_f32_16x16x32_bf16(zh, wl, aX, 0,0,0);
        aX = __builtin_amdgcn_mfma_f32_16x16x32_bf16(zl, wh, aX, 0,0,0);
      }
      {  // H scale: kstep1
        bf16x8 zh = *(const bf16x8*)(Zr + 1*32 + lq*8);
        bf16x8 zl = *(const bf16x8*)(Zr + 128 + 1*32 + lq*8);
        bf16x8 wh = *(const bf16x8*)(Wc + 1*32 + lq*8);
        bf16x8 wl = *(const bf16x8*)(Wc + 128 + 1*32 + lq*8);
        aH = __builtin_amdgcn_mfma_f32_16x16x32_bf16(zh, wh, aH, 0,0,0);
        aH = __builtin_amdgcn_mfma_f32_16x16x32_bf16(zh, wl, aH, 0,0,0);
        aH = __builtin_amdgcn_mfma_f32_16x16x32_bf16(zl, wh, aH, 0,0,0);
      }
      {  // C offset: ksteps 2,3
        bf16x8 zh = *(const bf16x8*)(Zr + 2*32 + lq*8);
        bf16x8 zl = *(const bf16x8*)(Zr + 128 + 2*32 + lq*8);
        bf16x8 wh = *(const bf16x8*)(Wc + 2*32 + lq*8);
        bf16x8 wl = *(const bf16x8*)(Wc + 128 + 2*32 + lq*8);
        aC = __builtin_amdgcn_mfma_f32_16x16x32_bf16(zh, wh, aC, 0,0,0);
        aC = __builtin_amdgcn_mfma_f32_16x16x32_bf16(zh, wl, aC, 0,0,0);
        aC = __builtin_amdgcn_mfma_f32_16x16x32_bf16(zl, wh, aC, 0,0,0);
        zh = *(const bf16x8*)(Zr + 3*32 + lq*8);
        zl = *(const bf16x8*)(Zr + 128 + 3*32 + lq*8);
        wh = *(const bf16x8*)(Wc + 3*32 + lq*8);
        wl = *(const bf16x8*)(Wc + 128 + 3*32 + lq*8);
        aC = __builtin_amdgcn_mfma_f32_16x16x32_bf16(zh, wh, aC, 0,0,0);
        aC = __builtin_amdgcn_mfma_f32_16x16x32_bf16(zh, wl, aC, 0,0,0);
        aC = __builtin_amdgcn_mfma_f32_16x16x32_bf16(zl, wh, aC, 0,0,0);
      }
      #pragma unroll
      for (int i = 0; i < 4; ++i) {
        long row = tm + wm*64 + m*16 + lq*4 + i;
        long col = (long)tn + wn*32 + n*16 + lr;
        gates[row*8192 + col] = (bf16_t)(aX[i]*accX[m][n][i] + aH[i]*accH[m][n][i] + aC[i]);
      }
    }
  }
}

// ---------------- hyper LSTM cell: 1 wave per batch row; sums 2 split-K partials ----------------
__global__ __launch_bounds__(64) void hyper_cell_k(const float* __restrict__ hcat_part,
                                                   const float* __restrict__ tc,
                                                   const float* __restrict__ h_bias,
                                                   const float* __restrict__ hg, const float* __restrict__ hb,
                                                   const float* __restrict__ hcg, const float* __restrict__ hcb,
                                                   float* __restrict__ out, float* __restrict__ hout) {
  const int b = blockIdx.x, l = threadIdx.x;
  const int u0 = 2 * l;
  float v[4][2], nv[4][2];
  #pragma unroll
  for (int g = 0; g < 4; ++g)
    #pragma unroll
    for (int p = 0; p < 2; ++p) {
      long idx = (long)b*512 + g*128 + u0 + p;
      float s = h_bias[g*128 + u0 + p];
      #pragma unroll
      for (int z = 0; z < 2; ++z) s += hcat_part[z*2097152L + idx];
      v[g][p] = s;
    }
  #pragma unroll
  for (int g = 0; g < 4; ++g) {
    float s = v[g][0] + v[g][1];
    float q = v[g][0]*v[g][0] + v[g][1]*v[g][1];
    #pragma unroll
    for (int m = 32; m >= 1; m >>= 1) { s += __shfl_xor(s, m); q += __shfl_xor(q, m); }
    float mean = s * (1.0f/128.0f);
    float inv = rsqrtf(q * (1.0f/128.0f) - mean*mean + EPS);
    #pragma unroll
    for (int p = 0; p < 2; ++p)
      nv[g][p] = (v[g][p] - mean) * inv * hg[g*128 + u0 + p] + hb[g*128 + u0 + p];
  }
  float nc[2], oo[2];
  #pragma unroll
  for (int p = 0; p < 2; ++p) {
    float ii = sigmoidf_(nv[0][p]);
    float jj = tanhf_(nv[1][p]);
    float ff = sigmoidf_(nv[2][p] + 1.0f);
    oo[p] = sigmoidf_(nv[3][p]);
    float hc = tc[(long)b*2176 + 2048 + u0 + p];
    nc[p] = hc * ff + ii * jj;
  }
  float s = nc[0] + nc[1], q = nc[0]*nc[0] + nc[1]*nc[1];
  #pragma unroll
  for (int m = 32; m >= 1; m >>= 1) { s += __shfl_xor(s, m); q += __shfl_xor(q, m); }
  float mean = s * (1.0f/128.0f);
  float inv = rsqrtf(q * (1.0f/128.0f) - mean*mean + EPS);
  #pragma unroll
  for (int p = 0; p < 2; ++p) {
    float nh = tanhf_((nc[p] - mean) * inv * hcg[u0 + p] + hcb[u0 + p]) * oo[p];
    out[OUT1 + (long)b*2176 + 2048 + u0 + p] = nc[p];
    out[OUT2 + (long)b*2176 + 2048 + u0 + p] = nh;
    hout[(long)b*128 + u0 + p] = nh;
  }
}

// ---------------- zhyper: zw/zb dots -> Zbig[4][4096][2][128] bf16 hi/lo ----------------
// 16 batch rows per block (256 blocks): weights stream once per 16 rows.
__global__ __launch_bounds__(192) void zhyper_k(const float* __restrict__ hout,
                                                const float* __restrict__ zwW, const float* __restrict__ zbias,
                                                const float* __restrict__ zbW,
                                                bf16_t* __restrict__ Zbig) {
  const int r0 = blockIdx.x * 16;
  const int t = threadIdx.x;
  __shared__ float ho[16][128];
  for (int i = t; i < 2048; i += 192) {
    int r = i >> 7, u = i & 127;
    ho[r][u] = hout[(long)(r0 + r)*128 + u];
  }
  // zero-fill pad segs 1,3 for all 4 gates (hi+lo) for these 16 rows
  if (t < 128) {
    int zg = t >> 5, zs = 1 + 2*((t >> 4) & 1), ze = t & 15;
    #pragma unroll
    for (int r = 0; r < 16; ++r) {
      long zbase = ((long)(zg*4096) + r0 + r)*256 + zs*16 + ze;
      Zbig[zbase] = (bf16_t)0.f; Zbig[zbase + 128] = (bf16_t)0.f;
    }
  }
  __syncthreads();
  const int k = t >> 4, e = t & 15;
  const float* wp = zwW + (long)k*2048 + e;
  const float* bp = zbW + (long)k*2048 + e;
  float a[16], a2[16];
  #pragma unroll
  for (int r = 0; r < 16; ++r) { a[r] = 0.f; a2[r] = 0.f; }
  for (int u0 = 0; u0 < 128; u0 += 8) {
    float wv[8], bv[8];
    #pragma unroll
    for (int j = 0; j < 8; ++j) { wv[j] = wp[(u0 + j)*16]; bv[j] = bp[(u0 + j)*16]; }
    #pragma unroll
    for (int r = 0; r < 16; ++r) {
      #pragma unroll
      for (int j = 0; j < 8; ++j) {
        float h = ho[r][u0 + j];
        a[r]  += h * wv[j];
        a2[r] += h * bv[j];
      }
    }
  }
  const float zb0 = zbias[k*16 + e];
  const int g = k & 3, kk = k >> 2;
  const int segA = kk*2;      // 0,2,4
  const int segB = kk + 5;    // 5,6,7
  #pragma unroll
  for (int r = 0; r < 16; ++r) {
    float av = a[r] + zb0;
    long baseg = ((long)(g*4096) + r0 + r)*256;
    bf16_t ah = (bf16_t)av;
    Zbig[baseg + segA*16 + e]       = ah;
    Zbig[baseg + 128 + segA*16 + e] = (bf16_t)(av - (float)ah);
    bf16_t bh = (bf16_t)a2[r];
    Zbig[baseg + segB*16 + e]       = bh;
    Zbig[baseg + 128 + segB*16 + e] = (bf16_t)(a2[r] - (float)bh);
  }
}

// ---------------- wbig: pack weights -> Wbig[4][2048][2][128] bf16 hi/lo (bias folded at seg 4) ----------------
__global__ __launch_bounds__(256) void wbig_k(const float* __restrict__ ww,
                                              const float* __restrict__ bw,
                                              const float* __restrict__ bias,
                                              bf16_t* __restrict__ Wbig) {
  int idx = blockIdx.x * 256 + threadIdx.x;   // 4*2048*16 = 131072 chunks of 8 k
  int c = idx & 15;
  int j = (idx >> 4) & 2047;
  int g = idx >> 15;
  int k0 = c * 8, seg = k0 >> 4, e0 = k0 & 15;
  float v[8];
  for (int u = 0; u < 8; ++u) v[u] = 0.f;
  if (seg == 0) {
    for (int u = 0; u < 8; ++u) v[u] = ww[(long)((g*16) + e0 + u)*2048 + j];
  } else if (seg == 2) {
    for (int u = 0; u < 8; ++u) v[u] = ww[(long)(((4+g)*16) + e0 + u)*2048 + j];
  } else if (seg == 4) {
    float bc = bias[g*2048 + j];
    for (int u = 0; u < 8; ++u) v[u] = ww[(long)(((8+g)*16) + e0 + u)*2048 + j] * bc;
  } else if (seg == 5) {
    for (int u = 0; u < 8; ++u) v[u] = bw[(long)((g*16) + e0 + u)*2048 + j];
  } else if (seg == 6) {
    for (int u = 0; u < 8; ++u) v[u] = bw[(long)(((4+g)*16) + e0 + u)*2048 + j];
  } else if (seg == 7) {
    for (int u = 0; u < 8; ++u) v[u] = bw[(long)(((8+g)*16) + e0 + u)*2048 + j];
  }
  bf16x8 hi, lo;
  for (int u = 0; u < 8; ++u) {
    bf16_t h = (bf16_t)v[u];
    hi[u] = h; lo[u] = (bf16_t)(v[u] - (float)h);
  }
  long base = ((long)(g*2048) + j)*256 + k0;
  *(bf16x8*)(Wbig + base)       = hi;
  *(bf16x8*)(Wbig + base + 128) = lo;
}

// ---------------- M2: main cell — 4 gate-LNs, LSTM update, c-LN, outputs (bf16 gates in) ----------------
__global__ __launch_bounds__(256) void cell_main_k(const bf16_t* __restrict__ gates,
                                                   const float* __restrict__ tc,
                                                   const float* __restrict__ lng, const float* __restrict__ lnb,
                                                   const float* __restrict__ lcg, const float* __restrict__ lcb,
                                                   float* __restrict__ out) {
  const int b = blockIdx.x, t = threadIdx.x;
  const int wave = t >> 6, lane = t & 63;
  const int j0 = t * 8;
  float gv[4][8], s[4], q[4];
  #pragma unroll
  for (int g = 0; g < 4; ++g) {
    bf16x8 v = *(const bf16x8*)(gates + (long)b*8192 + g*2048 + j0);
    float ls = 0.f, lq = 0.f;
    #pragma unroll
    for (int u = 0; u < 8; ++u) { float f = (float)v[u]; gv[g][u] = f; ls += f; lq += f*f; }
    s[g] = ls; q[g] = lq;
  }
  #pragma unroll
  for (int g = 0; g < 4; ++g)
    #pragma unroll
    for (int m = 32; m >= 1; m >>= 1) { s[g] += __shfl_xor(s[g], m); q[g] += __shfl_xor(q[g], m); }
  __shared__ float red[4][4][2];
  if (lane == 0) {
    #pragma unroll
    for (int g = 0; g < 4; ++g) { red[g][wave][0] = s[g]; red[g][wave][1] = q[g]; }
  }
  __syncthreads();
  float mean[4], inv[4];
  #pragma unroll
  for (int g = 0; g < 4; ++g) {
    float S = red[g][0][0] + red[g][1][0] + red[g][2][0] + red[g][3][0];
    float Q = red[g][0][1] + red[g][1][1] + red[g][2][1] + red[g][3][1];
    float m = S * (1.0f/2048.0f);
    mean[g] = m; inv[g] = rsqrtf(Q * (1.0f/2048.0f) - m*m + EPS);
  }
  float nc[8], oo[8];
  const float* cb = tc + (long)b*2176;
  #pragma unroll
  for (int u = 0; u < 8; ++u) {
    int j = j0 + u;
    float iv = (gv[0][u] - mean[0]) * inv[0] * lng[j]        + lnb[j];
    float jv = (gv[1][u] - mean[1]) * inv[1] * lng[2048 + j] + lnb[2048 + j];
    float fv = (gv[2][u] - mean[2]) * inv[2] * lng[4096 + j] + lnb[4096 + j];
    float ov = (gv[3][u] - mean[3]) * inv[3] * lng[6144 + j] + lnb[6144 + j];
    nc[u] = cb[j] * sigmoidf_(fv + 1.0f) + sigmoidf_(iv) * tanhf_(jv);
    oo[u] = sigmoidf_(ov);
  }
  float s2 = 0.f, q2 = 0.f;
  #pragma unroll
  for (int u = 0; u < 8; ++u) { s2 += nc[u]; q2 += nc[u]*nc[u]; }
  #pragma unroll
  for (int m = 32; m >= 1; m >>= 1) { s2 += __shfl_xor(s2, m); q2 += __shfl_xor(q2, m); }
  __syncthreads();
  if (lane == 0) { red[0][wave][0] = s2; red[0][wave][1] = q2; }
  __syncthreads();
  float S2 = red[0][0][0] + red[0][1][0] + red[0][2][0] + red[0][3][0];
  float Q2 = red[0][0][1] + red[0][1][1] + red[0][2][1] + red[0][3][1];
  float mc = S2 * (1.0f/2048.0f);
  float ic = rsqrtf(Q2 * (1.0f/2048.0f) - mc*mc + EPS);
  float nh[8];
  #pragma unroll
  for (int u = 0; u < 8; ++u)
    nh[u] = tanhf_((nc[u] - mc) * ic * lcg[j0 + u] + lcb[j0 + u]) * oo[u];
  float4 h0 = make_float4(nh[0], nh[1], nh[2], nh[3]);
  float4 h1 = make_float4(nh[4], nh[5], nh[6], nh[7]);
  float4 c0 = make_float4(nc[0], nc[1], nc[2], nc[3]);
  float4 c1 = make_float4(nc[4], nc[5], nc[6], nc[7]);
  *(float4*)(out + (long)b*2048 + j0)            = h0;
  *(float4*)(out + (long)b*2048 + j0 + 4)        = h1;
  *(float4*)(out + OUT1 + (long)b*2176 + j0)     = c0;
  *(float4*)(out + OUT1 + (long)b*2176 + j0 + 4) = c1;
  *(float4*)(out + OUT2 + (long)b*2176 + j0)     = h0;
  *(float4*)(out + OUT2 + (long)b*2176 + j0 + 4) = h1;
}

extern "C" void kernel_launch(void* const* d_in, const int* in_sizes, int n_in,
                              void* d_out, int out_size, void* d_ws, size_t ws_size,
                              hipStream_t stream) {
  const float* x      = (const float*)d_in[0];
  const float* tc     = (const float*)d_in[1];
  const float* th     = (const float*)d_in[2];
  const float* W_xh   = (const float*)d_in[3];
  const float* W_hh   = (const float*)d_in[4];
  const float* bias   = (const float*)d_in[5];
  const float* ln_g   = (const float*)d_in[6];
  const float* ln_b   = (const float*)d_in[7];
  const float* lnc_g  = (const float*)d_in[8];
  const float* lnc_b  = (const float*)d_in[9];
  const float* hW_xh  = (const float*)d_in[10];
  const float* hW_hh  = (const float*)d_in[11];
  const float* h_bias = (const float*)d_in[12];
  const float* h_ln_g = (const float*)d_in[13];
  const float* h_ln_b = (const float*)d_in[14];
  const float* h_lnc_g= (const float*)d_in[15];
  const float* h_lnc_b= (const float*)d_in[16];
  const float* hyp_zw = (const float*)d_in[17];
  const float* hyp_zb = (const float*)d_in[18];
  const float* hyp_ww = (const float*)d_in[19];
  const float* hyp_zbw= (const float*)d_in[20];
  const float* hyp_bw = (const float*)d_in[21];
  float* out = (float*)d_out;

  // Workspace layout. Total ~166 MB (gates bf16, 2 hcat partials).
  char* w = (char*)d_ws;
  bf16_t* A        = (bf16_t*)w;  w += 4096L*3200*2;   //  26,214,400
  bf16_t* WtALL    = (bf16_t*)w;  w += 8192L*3072*2;   //  50,331,648
  bf16_t* WtCAT    = (bf16_t*)w;  w += 512L*3200*2;    //   3,276,800
  float*  hcat_part= (float*)w;   w += 2L*4096*512*4;  //  16,777,216
  float*  hout     = (float*)w;   w += 4096L*128*4;    //   2,097,152
  bf16_t* Zbig     = (bf16_t*)w;  w += 4L*4096*256*2;  //   8,388,608
  bf16_t* Wbig     = (bf16_t*)w;  w += 4L*2048*256*2;  //   4,194,304
  bf16_t* gates    = (bf16_t*)w;  w += 4096L*8192*2;   //  67,108,864

  build_A_k<<<2048, 256, 0, stream>>>(x, th, A);
  transpose_conv_k<<<dim3(256, 96),  dim3(32, 8), 0, stream>>>(W_xh, 1024, W_hh, 3072, 8192, WtALL);
  transpose_conv_k<<<dim3(16, 100),  dim3(32, 8), 0, stream>>>(hW_xh, 3072, hW_hh, 3200, 512, WtCAT);
  gemm_bf16_k<float><<<dim3(4, 32, 2), 256, 0, stream>>>(A, 3200, WtCAT, 3200, hcat_part, 512, 1600, 4096L*512);
  hyper_cell_k<<<4096, 64, 0, stream>>>(hcat_part, tc, h_bias, h_ln_g, h_ln_b, h_lnc_g, h_lnc_b, out, hout);
  zhyper_k<<<256, 192, 0, stream>>>(hout, hyp_zw, hyp_zb, hyp_zbw, Zbig);
  wbig_k<<<512, 256, 0, stream>>>(hyp_ww, hyp_bw, bias, Wbig);
  gemm_fused2_k<<<dim3(64, 32), 512, 0, stream>>>(A, WtALL, Zbig, Wbig, gates);
  cell_main_k<<<4096, 256, 0, stream>>>(gates, tc, ln_g, ln_b, lnc_g, lnc_b, out);
}